// Round 1
// baseline (835.377 us; speedup 1.0000x reference)
//
#include <hip/hip_runtime.h>
#include <stdint.h>

// ---------------------------------------------------------------------------
// DTransformer layer on MI355X.
// B=4, T=1024, D=1024, H=16, dk=64.  All shapes hardcoded.
// Pipeline:
//   1. convert f32 -> bf16 (query,key,values,Wq,Wv,Wo)
//   2. gemm_proj (z=0,1,2): Q=q@Wq^T+bq, K=k@Wq^T+bq, V=v@Wv^T+bv -> (B,H,T,64) bf16
//   3. attn: per (b,h,16-row block): QK^T (MFMA) -> softmax -> suffix-cumsum ->
//            gamma distance effect -> softmax -> maxout -> PV (VALU) -> concat bf16
//   4. gemm_out: x = concat@Wo^T + bo + query   (f32)
//   5. layernorm -> d_out (f32)
// ---------------------------------------------------------------------------

typedef unsigned short ushort_t;
typedef __attribute__((ext_vector_type(8))) short short8;
typedef __attribute__((ext_vector_type(4))) float f32x4;
typedef __attribute__((ext_vector_type(4))) unsigned short u16x4;

#define GLB_CAST(p) ((const __attribute__((address_space(1))) void*)(p))
#define LDS_CAST(p) ((__attribute__((address_space(3))) void*)(p))

__device__ __forceinline__ float b2f(ushort_t u) {
  union { unsigned int i; float f; } x; x.i = ((unsigned int)u) << 16; return x.f;
}
__device__ __forceinline__ ushort_t f2b(float f) {
  union { float f; unsigned int i; } u; u.f = f;
  unsigned int r = u.i + 0x7FFFu + ((u.i >> 16) & 1u);   // RNE
  return (ushort_t)(r >> 16);
}
__device__ __forceinline__ float wave_max(float v) {
  #pragma unroll
  for (int d = 32; d > 0; d >>= 1) v = fmaxf(v, __shfl_xor(v, d));
  return v;
}
__device__ __forceinline__ float wave_sum(float v) {
  #pragma unroll
  for (int d = 32; d > 0; d >>= 1) v += __shfl_xor(v, d);
  return v;
}

// ---------------------------------------------------------------------------
// f32 -> bf16 convert (vectorized float4 -> 4x bf16)
// ---------------------------------------------------------------------------
__global__ void conv_f32_bf16(const float* __restrict__ src, ushort_t* __restrict__ dst, int n4) {
  int i = blockIdx.x * blockDim.x + threadIdx.x;
  if (i < n4) {
    const float4 v = reinterpret_cast<const float4*>(src)[i];
    u16x4 o;
    o[0] = f2b(v.x); o[1] = f2b(v.y); o[2] = f2b(v.z); o[3] = f2b(v.w);
    reinterpret_cast<u16x4*>(dst)[i] = o;
  }
}

// ---------------------------------------------------------------------------
// 128x128 tile bf16 GEMM core (m97 structure): C[m,n] = sum_k A[m,k]*Bt[n,k]
// A: [4096][1024] bf16 row-major, Bt: [1024][1024] bf16 row-major (N x K).
// 256 threads, 4 waves, each wave a 64x64 sub-tile of 16x16x32 MFMA frags.
// ---------------------------------------------------------------------------
__device__ __forceinline__ void gemm_core(const ushort_t* __restrict__ A,
                                          const ushort_t* __restrict__ Bt,
                                          int m0, int n0,
                                          ushort_t* As, ushort_t* Bs,
                                          f32x4 (&acc)[4][4]) {
  const int tid = threadIdx.x, lane = tid & 63;
  const int wid = tid >> 6;
  const int wr = (wid >> 1) * 64, wc = (wid & 1) * 64;
  for (int k0 = 0; k0 < 1024; k0 += 32) {
    #pragma unroll
    for (int it = 0; it < 2; ++it) {
      const int idx = tid * 8 + it * 2048;            // element index in 128x32 tile
      const int r = idx >> 5, kk = idx & 31;
      __builtin_amdgcn_global_load_lds(GLB_CAST(&A[(size_t)(m0 + r) * 1024 + k0 + kk]),
                                       LDS_CAST(&As[idx]), 16, 0, 0);
      __builtin_amdgcn_global_load_lds(GLB_CAST(&Bt[(size_t)(n0 + r) * 1024 + k0 + kk]),
                                       LDS_CAST(&Bs[idx]), 16, 0, 0);
    }
    __syncthreads();   // compiler drains vmcnt before barrier
    short8 af[4], bfv[4];
    #pragma unroll
    for (int m = 0; m < 4; ++m)
      af[m] = *reinterpret_cast<const short8*>(&As[(wr + m * 16 + (lane & 15)) * 32 + (lane >> 4) * 8]);
    #pragma unroll
    for (int n = 0; n < 4; ++n)
      bfv[n] = *reinterpret_cast<const short8*>(&Bs[(wc + n * 16 + (lane & 15)) * 32 + (lane >> 4) * 8]);
    #pragma unroll
    for (int m = 0; m < 4; ++m)
      #pragma unroll
      for (int n = 0; n < 4; ++n)
        acc[m][n] = __builtin_amdgcn_mfma_f32_16x16x32_bf16(af[m], bfv[n], acc[m][n], 0, 0, 0);
    __syncthreads();
  }
}

// QKV projections.  z=0: Q=qb@Wq, z=1: K=kb@Wq, z=2: V=vb@Wv.  Output in
// head layout (B,H,T,64) bf16 with bias.
__global__ __launch_bounds__(256) void gemm_proj(
    const ushort_t* __restrict__ qb, const ushort_t* __restrict__ kb, const ushort_t* __restrict__ vb,
    const ushort_t* __restrict__ Wqb, const ushort_t* __restrict__ Wvb,
    const float* __restrict__ bq, const float* __restrict__ bvv,
    ushort_t* __restrict__ Qh, ushort_t* __restrict__ Kh, ushort_t* __restrict__ Vh) {
  __shared__ ushort_t As[128 * 32], Bs[128 * 32];
  const ushort_t* A; const ushort_t* Bt; const float* bias; ushort_t* dst;
  if (blockIdx.z == 0)      { A = qb; Bt = Wqb; bias = bq;  dst = Qh; }
  else if (blockIdx.z == 1) { A = kb; Bt = Wqb; bias = bq;  dst = Kh; }
  else                      { A = vb; Bt = Wvb; bias = bvv; dst = Vh; }
  const int m0 = blockIdx.y * 128, n0 = blockIdx.x * 128;
  f32x4 zero = {0.f, 0.f, 0.f, 0.f};
  f32x4 acc[4][4];
  #pragma unroll
  for (int m = 0; m < 4; ++m)
    #pragma unroll
    for (int n = 0; n < 4; ++n) acc[m][n] = zero;
  gemm_core(A, Bt, m0, n0, As, Bs, acc);
  const int lane = threadIdx.x & 63, wid = threadIdx.x >> 6;
  const int wr = (wid >> 1) * 64, wc = (wid & 1) * 64;
  #pragma unroll
  for (int m = 0; m < 4; ++m)
    #pragma unroll
    for (int n = 0; n < 4; ++n)
      #pragma unroll
      for (int r4 = 0; r4 < 4; ++r4) {
        const int row = m0 + wr + m * 16 + (lane >> 4) * 4 + r4;   // token index
        const int col = n0 + wc + n * 16 + (lane & 15);            // output dim
        const float v = acc[m][n][r4] + bias[col];
        const int b = row >> 10, t = row & 1023, h = col >> 6, dd = col & 63;
        dst[((size_t)(b * 16 + h) * 1024 + t) * 64 + dd] = f2b(v);
      }
}

// Output projection: x = concat@Wo^T + bo + query   (f32)
__global__ __launch_bounds__(256) void gemm_out(
    const ushort_t* __restrict__ A, const ushort_t* __restrict__ Bt,
    const float* __restrict__ bias, const float* __restrict__ resid,
    float* __restrict__ dstF) {
  __shared__ ushort_t As[128 * 32], Bs[128 * 32];
  const int m0 = blockIdx.y * 128, n0 = blockIdx.x * 128;
  f32x4 zero = {0.f, 0.f, 0.f, 0.f};
  f32x4 acc[4][4];
  #pragma unroll
  for (int m = 0; m < 4; ++m)
    #pragma unroll
    for (int n = 0; n < 4; ++n) acc[m][n] = zero;
  gemm_core(A, Bt, m0, n0, As, Bs, acc);
  const int lane = threadIdx.x & 63, wid = threadIdx.x >> 6;
  const int wr = (wid >> 1) * 64, wc = (wid & 1) * 64;
  #pragma unroll
  for (int m = 0; m < 4; ++m)
    #pragma unroll
    for (int n = 0; n < 4; ++n)
      #pragma unroll
      for (int r4 = 0; r4 < 4; ++r4) {
        const int row = m0 + wr + m * 16 + (lane >> 4) * 4 + r4;
        const int col = n0 + wc + n * 16 + (lane & 15);
        const size_t o = (size_t)row * 1024 + col;
        dstF[o] = acc[m][n][r4] + bias[col] + resid[o];
      }
}

// ---------------------------------------------------------------------------
// Attention.  grid = (T/16, B*H), 256 threads (4 waves).
// Phase A: S[16][1024] = Q_tile @ K^T / 8 via MFMA (bounded causally).
// Phase B: per wave, 4 rows: softmax -> suffix-cumsum tail -> gamma effect ->
//          softmax -> maxout scale; write p back into S.
// Phase C: out[i][d] = sum_j p[j] * V[j][d]  (lane = d, p broadcast via LDS).
// ---------------------------------------------------------------------------
__global__ __launch_bounds__(256) void attn_kernel(
    const ushort_t* __restrict__ Qh, const ushort_t* __restrict__ Kh,
    const ushort_t* __restrict__ Vh, const float* __restrict__ gammas,
    ushort_t* __restrict__ concat) {
  __shared__ float S[16][1024];
  __shared__ ushort_t Qs[16 * 64];
  const int tid = threadIdx.x, lane = tid & 63, w = tid >> 6;
  const int bh = blockIdx.y, b = bh >> 4, h = bh & 15;
  const int i0 = blockIdx.x * 16;
  const size_t base = (size_t)bh * (1024 * 64);

  { // stage Q tile (16 rows x 64)
    const int r = tid >> 4, d = (tid & 15) * 4;
    *reinterpret_cast<u16x4*>(&Qs[r * 64 + d]) =
        *reinterpret_cast<const u16x4*>(&Qh[base + (size_t)(i0 + r) * 64 + d]);
  }
  __syncthreads();

  // ---- Phase A: scores ----
  const int upper = i0 + 16;            // need cols j < upper
  for (int nt = 0; nt < 16; ++nt) {
    const int colbase = (nt * 4 + w) * 16;   // round-robin tiles across waves
    if (colbase >= upper) break;
    f32x4 acc = {0.f, 0.f, 0.f, 0.f};
    #pragma unroll
    for (int kt = 0; kt < 2; ++kt) {
      const short8 a = *reinterpret_cast<const short8*>(
          &Qs[(lane & 15) * 64 + kt * 32 + (lane >> 4) * 8]);
      const short8 bb = *reinterpret_cast<const short8*>(
          &Kh[base + (size_t)(colbase + (lane & 15)) * 64 + kt * 32 + (lane >> 4) * 8]);
      acc = __builtin_amdgcn_mfma_f32_16x16x32_bf16(a, bb, acc, 0, 0, 0);
    }
    #pragma unroll
    for (int r4 = 0; r4 < 4; ++r4)
      S[(lane >> 4) * 4 + r4][colbase + (lane & 15)] = acc[r4] * 0.125f;
  }
  __syncthreads();

  // ---- Phase B: softmax machinery, 4 rows per wave ----
  const float gam = fabsf(gammas[h]);
  for (int rr = 0; rr < 4; ++rr) {
    const int r = w * 4 + rr;
    const int i = i0 + r;
    if (i == 0) continue;                 // row 0: everything masked -> p = 0
    float sv[16], ev[16], tl[16];
    #pragma unroll
    for (int jb = 0; jb < 16; ++jb) {
      const int j = jb * 64 + lane;
      sv[jb] = (j < i) ? S[r][j] : -__builtin_inff();
    }
    float m1 = sv[0];
    #pragma unroll
    for (int jb = 1; jb < 16; ++jb) m1 = fmaxf(m1, sv[jb]);
    m1 = wave_max(m1);
    float zl = 0.f;
    #pragma unroll
    for (int jb = 0; jb < 16; ++jb) {
      const int j = jb * 64 + lane;
      ev[jb] = (j < i) ? __expf(sv[jb] - m1) : 0.f;
      zl += ev[jb];
    }
    const float Z1 = wave_sum(zl);
    // inclusive suffix across lanes per jb
    #pragma unroll
    for (int jb = 0; jb < 16; ++jb) {
      float v = ev[jb];
      #pragma unroll
      for (int dd = 1; dd < 64; dd <<= 1) {
        const float t = __shfl_down(v, dd);
        v += (lane + dd < 64) ? t : 0.f;
      }
      tl[jb] = v;
    }
    // combine with block-level suffix: tail[j] = sum_{j' > j} e[j']
    float run = 0.f;
    #pragma unroll
    for (int jb = 15; jb >= 0; --jb) {
      const float bs = __shfl(tl[jb], 0);   // total of this 64-col block
      tl[jb] = tl[jb] - ev[jb] + run;       // exclusive-in-lane + later blocks
      run += bs;
    }
    const float invZ1 = 1.f / Z1;
    float m2l = -__builtin_inff();
    #pragma unroll
    for (int jb = 0; jb < 16; ++jb) {
      const int j = jb * 64 + lane;
      if (j < i) {
        const float pos = (float)(i - j);
        const float dist = sqrtf(fmaxf(tl[jb] * invZ1 * pos, 0.f));
        const float eff = fmaxf(__expf(-gam * dist), 1e-5f);
        sv[jb] *= eff;
      }
      m2l = fmaxf(m2l, sv[jb]);
    }
    const float m2 = wave_max(m2l);
    float z2l = 0.f;
    #pragma unroll
    for (int jb = 0; jb < 16; ++jb) {
      const int j = jb * 64 + lane;
      ev[jb] = (j < i) ? __expf(sv[jb] - m2) : 0.f;
      z2l += ev[jb];
    }
    const float Z2 = wave_sum(z2l);
    const float sc = fminf(Z2, 5.f) / Z2;   // maxout: max p = 1/Z2
    #pragma unroll
    for (int jb = 0; jb < 16; ++jb)
      S[r][jb * 64 + lane] = ev[jb] * sc;
  }
  __syncthreads();

  // ---- Phase C: PV ----
  const ushort_t* __restrict__ Vus = Vh + base;
  for (int rr = 0; rr < 4; ++rr) {
    const int r = w * 4 + rr;
    const int i = i0 + r;
    float acc0 = 0.f, acc1 = 0.f;
    int j = 0;
    for (; j + 8 <= i; j += 8) {
      const float4 p0 = *reinterpret_cast<const float4*>(&S[r][j]);
      const float4 p1 = *reinterpret_cast<const float4*>(&S[r][j + 4]);
      const ushort_t v0 = Vus[(size_t)(j + 0) * 64 + lane];
      const ushort_t v1 = Vus[(size_t)(j + 1) * 64 + lane];
      const ushort_t v2 = Vus[(size_t)(j + 2) * 64 + lane];
      const ushort_t v3 = Vus[(size_t)(j + 3) * 64 + lane];
      const ushort_t v4 = Vus[(size_t)(j + 4) * 64 + lane];
      const ushort_t v5 = Vus[(size_t)(j + 5) * 64 + lane];
      const ushort_t v6 = Vus[(size_t)(j + 6) * 64 + lane];
      const ushort_t v7 = Vus[(size_t)(j + 7) * 64 + lane];
      acc0 = fmaf(p0.x, b2f(v0), acc0);
      acc0 = fmaf(p0.y, b2f(v1), acc0);
      acc0 = fmaf(p0.z, b2f(v2), acc0);
      acc0 = fmaf(p0.w, b2f(v3), acc0);
      acc1 = fmaf(p1.x, b2f(v4), acc1);
      acc1 = fmaf(p1.y, b2f(v5), acc1);
      acc1 = fmaf(p1.z, b2f(v6), acc1);
      acc1 = fmaf(p1.w, b2f(v7), acc1);
    }
    for (; j < i; ++j) acc0 = fmaf(S[r][j], b2f(Vus[(size_t)j * 64 + lane]), acc0);
    concat[((size_t)(b * 1024 + i)) * 1024 + h * 64 + lane] = f2b(acc0 + acc1);
  }
}

// ---------------------------------------------------------------------------
// LayerNorm over D=1024 (biased var), out = (x-mu)/sqrt(var+1e-5)*g + b
// ---------------------------------------------------------------------------
__global__ __launch_bounds__(256) void ln_kernel(const float* __restrict__ x,
                                                 const float* __restrict__ g,
                                                 const float* __restrict__ bb,
                                                 float* __restrict__ out) {
  const int row = blockIdx.x, tid = threadIdx.x, lane = tid & 63, w = tid >> 6;
  const float4 v = reinterpret_cast<const float4*>(x + (size_t)row * 1024)[tid];
  float s = v.x + v.y + v.z + v.w;
  float q = v.x * v.x + v.y * v.y + v.z * v.z + v.w * v.w;
  s = wave_sum(s); q = wave_sum(q);
  __shared__ float ps[4], pq[4];
  if (lane == 0) { ps[w] = s; pq[w] = q; }
  __syncthreads();
  const float ts = ps[0] + ps[1] + ps[2] + ps[3];
  const float tq = pq[0] + pq[1] + pq[2] + pq[3];
  const float mu = ts * (1.f / 1024.f);
  const float inv = rsqrtf(tq * (1.f / 1024.f) - mu * mu + 1e-5f);
  const float4 gv = reinterpret_cast<const float4*>(g)[tid];
  const float4 bv = reinterpret_cast<const float4*>(bb)[tid];
  float4 o;
  o.x = (v.x - mu) * inv * gv.x + bv.x;
  o.y = (v.y - mu) * inv * gv.y + bv.y;
  o.z = (v.z - mu) * inv * gv.z + bv.z;
  o.w = (v.w - mu) * inv * gv.w + bv.w;
  reinterpret_cast<float4*>(out + (size_t)row * 1024)[tid] = o;
}

// ---------------------------------------------------------------------------
extern "C" void kernel_launch(void* const* d_in, const int* in_sizes, int n_in,
                              void* d_out, int out_size, void* d_ws, size_t ws_size,
                              hipStream_t stream) {
  (void)in_sizes; (void)n_in; (void)out_size; (void)ws_size;
  const float* query  = (const float*)d_in[0];
  const float* key    = (const float*)d_in[1];
  const float* values = (const float*)d_in[2];
  const float* Wq     = (const float*)d_in[3];
  const float* bq     = (const float*)d_in[4];
  const float* Wv     = (const float*)d_in[5];
  const float* bv     = (const float*)d_in[6];
  const float* Wo     = (const float*)d_in[7];
  const float* bo     = (const float*)d_in[8];
  const float* gammas = (const float*)d_in[9];
  const float* ln_g   = (const float*)d_in[10];
  const float* ln_b   = (const float*)d_in[11];
  float* out = (float*)d_out;

  const size_t NT = 4096ull * 1024;     // tokens x D elements
  const size_t NW = 1024ull * 1024;     // weight elements
  char* p = (char*)d_ws;
  ushort_t* qb  = (ushort_t*)p; p += NT * 2;
  ushort_t* kb  = (ushort_t*)p; p += NT * 2;
  ushort_t* vb  = (ushort_t*)p; p += NT * 2;
  ushort_t* Wqb = (ushort_t*)p; p += NW * 2;
  ushort_t* Wvb = (ushort_t*)p; p += NW * 2;
  ushort_t* Wob = (ushort_t*)p; p += NW * 2;
  ushort_t* Qh  = (ushort_t*)p; p += NT * 2;
  ushort_t* Kh  = (ushort_t*)p; p += NT * 2;
  ushort_t* Vh  = (ushort_t*)p; p += NT * 2;
  // aliases (stream-ordered reuse):
  ushort_t* concat = vb;                // free after gemm_proj
  float*    xbuf   = (float*)qb;        // spans qb+kb (16 MB), free after gemm_proj

  conv_f32_bf16<<<4096, 256, 0, stream>>>(query,  qb, (int)(NT / 4));
  conv_f32_bf16<<<4096, 256, 0, stream>>>(key,    kb, (int)(NT / 4));
  conv_f32_bf16<<<4096, 256, 0, stream>>>(values, vb, (int)(NT / 4));
  conv_f32_bf16<<<1024, 256, 0, stream>>>(Wq, Wqb, (int)(NW / 4));
  conv_f32_bf16<<<1024, 256, 0, stream>>>(Wv, Wvb, (int)(NW / 4));
  conv_f32_bf16<<<1024, 256, 0, stream>>>(Wo, Wob, (int)(NW / 4));

  gemm_proj<<<dim3(8, 32, 3), 256, 0, stream>>>(qb, kb, vb, Wqb, Wvb, bq, bv, Qh, Kh, Vh);
  attn_kernel<<<dim3(64, 64), 256, 0, stream>>>(Qh, Kh, Vh, gammas, concat);
  gemm_out<<<dim3(8, 32), 256, 0, stream>>>(concat, Wob, bo, query, xbuf);
  ln_kernel<<<4096, 256, 0, stream>>>(xbuf, ln_g, ln_b, out);
}

// Round 2
// 408.617 us; speedup vs baseline: 2.0444x; 2.0444x over previous
//
#include <hip/hip_runtime.h>
#include <stdint.h>

// ---------------------------------------------------------------------------
// DTransformer layer on MI355X.  B=4, T=1024, D=1024, H=16, dk=64.
//   1. convert f32 -> bf16
//   2. gemm_proj: Q,K (head layout B,H,T,64), V -> TRANSPOSED (B,H,64,T)
//   3. attn: QK^T (MFMA) -> softmax -> suffix-scan -> gamma effect -> softmax
//            -> maxout -> P stored bf16 (XOR-swizzled) -> PV via MFMA
//   4. gemm_out: x = concat@Wo^T + bo + query   5. layernorm
// ---------------------------------------------------------------------------

typedef unsigned short ushort_t;
typedef __attribute__((ext_vector_type(8))) short short8;
typedef __attribute__((ext_vector_type(4))) float f32x4;
typedef __attribute__((ext_vector_type(4))) unsigned short u16x4;

#define GLB_CAST(p) ((const __attribute__((address_space(1))) void*)(p))
#define LDS_CAST(p) ((__attribute__((address_space(3))) void*)(p))

__device__ __forceinline__ float b2f(ushort_t u) {
  union { unsigned int i; float f; } x; x.i = ((unsigned int)u) << 16; return x.f;
}
__device__ __forceinline__ ushort_t f2b(float f) {
  union { float f; unsigned int i; } u; u.f = f;
  unsigned int r = u.i + 0x7FFFu + ((u.i >> 16) & 1u);   // RNE
  return (ushort_t)(r >> 16);
}
__device__ __forceinline__ float wave_max(float v) {
  #pragma unroll
  for (int d = 32; d > 0; d >>= 1) v = fmaxf(v, __shfl_xor(v, d));
  return v;
}
__device__ __forceinline__ float wave_sum(float v) {
  #pragma unroll
  for (int d = 32; d > 0; d >>= 1) v += __shfl_xor(v, d);
  return v;
}

// ---------------------------------------------------------------------------
__global__ void conv_f32_bf16(const float* __restrict__ src, ushort_t* __restrict__ dst, int n4) {
  int i = blockIdx.x * blockDim.x + threadIdx.x;
  if (i < n4) {
    const float4 v = reinterpret_cast<const float4*>(src)[i];
    u16x4 o;
    o[0] = f2b(v.x); o[1] = f2b(v.y); o[2] = f2b(v.z); o[3] = f2b(v.w);
    reinterpret_cast<u16x4*>(dst)[i] = o;
  }
}

// ---------------------------------------------------------------------------
// 128x128 tile bf16 GEMM core: C[m,n] = sum_k A[m,k]*Bt[n,k]
// ---------------------------------------------------------------------------
__device__ __forceinline__ void gemm_core(const ushort_t* __restrict__ A,
                                          const ushort_t* __restrict__ Bt,
                                          int m0, int n0,
                                          ushort_t* As, ushort_t* Bs,
                                          f32x4 (&acc)[4][4]) {
  const int tid = threadIdx.x, lane = tid & 63;
  const int wid = tid >> 6;
  const int wr = (wid >> 1) * 64, wc = (wid & 1) * 64;
  for (int k0 = 0; k0 < 1024; k0 += 32) {
    #pragma unroll
    for (int it = 0; it < 2; ++it) {
      const int idx = tid * 8 + it * 2048;            // element index in 128x32 tile
      const int r = idx >> 5, kk = idx & 31;
      __builtin_amdgcn_global_load_lds(GLB_CAST(&A[(size_t)(m0 + r) * 1024 + k0 + kk]),
                                       LDS_CAST(&As[idx]), 16, 0, 0);
      __builtin_amdgcn_global_load_lds(GLB_CAST(&Bt[(size_t)(n0 + r) * 1024 + k0 + kk]),
                                       LDS_CAST(&Bs[idx]), 16, 0, 0);
    }
    __syncthreads();
    short8 af[4], bfv[4];
    #pragma unroll
    for (int m = 0; m < 4; ++m)
      af[m] = *reinterpret_cast<const short8*>(&As[(wr + m * 16 + (lane & 15)) * 32 + (lane >> 4) * 8]);
    #pragma unroll
    for (int n = 0; n < 4; ++n)
      bfv[n] = *reinterpret_cast<const short8*>(&Bs[(wc + n * 16 + (lane & 15)) * 32 + (lane >> 4) * 8]);
    #pragma unroll
    for (int m = 0; m < 4; ++m)
      #pragma unroll
      for (int n = 0; n < 4; ++n)
        acc[m][n] = __builtin_amdgcn_mfma_f32_16x16x32_bf16(af[m], bfv[n], acc[m][n], 0, 0, 0);
    __syncthreads();
  }
}

// QKV projections. z=0: Q, z=1: K -> (B,H,T,64); z=2: V -> TRANSPOSED (B,H,64,T)
__global__ __launch_bounds__(256) void gemm_proj(
    const ushort_t* __restrict__ qb, const ushort_t* __restrict__ kb, const ushort_t* __restrict__ vb,
    const ushort_t* __restrict__ Wqb, const ushort_t* __restrict__ Wvb,
    const float* __restrict__ bq, const float* __restrict__ bvv,
    ushort_t* __restrict__ Qh, ushort_t* __restrict__ Kh, ushort_t* __restrict__ Vt) {
  __shared__ ushort_t As[128 * 32], Bs[128 * 32];
  const ushort_t* A; const ushort_t* Bt; const float* bias;
  if (blockIdx.z == 0)      { A = qb; Bt = Wqb; bias = bq;  }
  else if (blockIdx.z == 1) { A = kb; Bt = Wqb; bias = bq;  }
  else                      { A = vb; Bt = Wvb; bias = bvv; }
  const int m0 = blockIdx.y * 128, n0 = blockIdx.x * 128;
  f32x4 zero = {0.f, 0.f, 0.f, 0.f};
  f32x4 acc[4][4];
  #pragma unroll
  for (int m = 0; m < 4; ++m)
    #pragma unroll
    for (int n = 0; n < 4; ++n) acc[m][n] = zero;
  gemm_core(A, Bt, m0, n0, As, Bs, acc);
  const int lane = threadIdx.x & 63, wid = threadIdx.x >> 6;
  const int wr = (wid >> 1) * 64, wc = (wid & 1) * 64;
  if (blockIdx.z == 2) {
    // V transposed: Vt[((b*16+h)*64+dd)*1024 + t], pack 4 consecutive tokens
    #pragma unroll
    for (int m = 0; m < 4; ++m)
      #pragma unroll
      for (int n = 0; n < 4; ++n) {
        const int rowb = m0 + wr + m * 16 + (lane >> 4) * 4;   // token base (mult of 4)
        const int col  = n0 + wc + n * 16 + (lane & 15);       // output dim
        u16x4 pk;
        #pragma unroll
        for (int r4 = 0; r4 < 4; ++r4) pk[r4] = f2b(acc[m][n][r4] + bias[col]);
        const int bi = rowb >> 10, t = rowb & 1023;
        *reinterpret_cast<u16x4*>(
            &Vt[((size_t)(bi * 16 + (col >> 6)) * 64 + (col & 63)) * 1024 + t]) = pk;
      }
  } else {
    ushort_t* dst = (blockIdx.z == 0) ? Qh : Kh;
    #pragma unroll
    for (int m = 0; m < 4; ++m)
      #pragma unroll
      for (int n = 0; n < 4; ++n)
        #pragma unroll
        for (int r4 = 0; r4 < 4; ++r4) {
          const int row = m0 + wr + m * 16 + (lane >> 4) * 4 + r4;
          const int col = n0 + wc + n * 16 + (lane & 15);
          const float v = acc[m][n][r4] + bias[col];
          const int bi = row >> 10, t = row & 1023, h = col >> 6, dd = col & 63;
          dst[((size_t)(bi * 16 + h) * 1024 + t) * 64 + dd] = f2b(v);
        }
  }
}

// Output projection: x = concat@Wo^T + bo + query   (f32)
__global__ __launch_bounds__(256) void gemm_out(
    const ushort_t* __restrict__ A, const ushort_t* __restrict__ Bt,
    const float* __restrict__ bias, const float* __restrict__ resid,
    float* __restrict__ dstF) {
  __shared__ ushort_t As[128 * 32], Bs[128 * 32];
  const int m0 = blockIdx.y * 128, n0 = blockIdx.x * 128;
  f32x4 zero = {0.f, 0.f, 0.f, 0.f};
  f32x4 acc[4][4];
  #pragma unroll
  for (int m = 0; m < 4; ++m)
    #pragma unroll
    for (int n = 0; n < 4; ++n) acc[m][n] = zero;
  gemm_core(A, Bt, m0, n0, As, Bs, acc);
  const int lane = threadIdx.x & 63, wid = threadIdx.x >> 6;
  const int wr = (wid >> 1) * 64, wc = (wid & 1) * 64;
  #pragma unroll
  for (int m = 0; m < 4; ++m)
    #pragma unroll
    for (int n = 0; n < 4; ++n)
      #pragma unroll
      for (int r4 = 0; r4 < 4; ++r4) {
        const int row = m0 + wr + m * 16 + (lane >> 4) * 4 + r4;
        const int col = n0 + wc + n * 16 + (lane & 15);
        const size_t o = (size_t)row * 1024 + col;
        dstF[o] = acc[m][n][r4] + bias[col] + resid[o];
      }
}

// ---------------------------------------------------------------------------
// Attention.  grid = (T/16, B*H), 256 threads (4 waves).
// Phase A: S[16][1024] = Q_tile @ K^T / 8 via MFMA (causally bounded).
// Phase B: per wave, 4 rows: softmax -> suffix-scan -> gamma effect -> softmax
//          -> maxout; write P as bf16 into S row (ushort view, chunk-XOR swz).
// Phase C: per wave one 16-wide d-tile: out = P @ V via MFMA (Vt from global).
// ---------------------------------------------------------------------------
__global__ __launch_bounds__(256) void attn_kernel(
    const ushort_t* __restrict__ Qh, const ushort_t* __restrict__ Kh,
    const ushort_t* __restrict__ Vt, const float* __restrict__ gammas,
    ushort_t* __restrict__ concat) {
  __shared__ float S[16][1024];
  __shared__ ushort_t Qs[16 * 64];
  const int tid = threadIdx.x, lane = tid & 63, w = tid >> 6;
  const int bh = blockIdx.y, bi = bh >> 4, h = bh & 15;
  const int i0 = blockIdx.x * 16;
  const size_t base = (size_t)bh * (1024 * 64);

  { // stage Q tile (16 rows x 64)
    const int r = tid >> 4, d = (tid & 15) * 4;
    *reinterpret_cast<u16x4*>(&Qs[r * 64 + d]) =
        *reinterpret_cast<const u16x4*>(&Qh[base + (size_t)(i0 + r) * 64 + d]);
  }
  __syncthreads();

  // ---- Phase A: scores ----
  const int upper = i0 + 16;
  for (int nt = 0; nt < 16; ++nt) {
    const int colbase = (nt * 4 + w) * 16;
    if (colbase >= upper) break;
    f32x4 acc = {0.f, 0.f, 0.f, 0.f};
    #pragma unroll
    for (int kt = 0; kt < 2; ++kt) {
      const short8 a = *reinterpret_cast<const short8*>(
          &Qs[(lane & 15) * 64 + kt * 32 + (lane >> 4) * 8]);
      const short8 bb = *reinterpret_cast<const short8*>(
          &Kh[base + (size_t)(colbase + (lane & 15)) * 64 + kt * 32 + (lane >> 4) * 8]);
      acc = __builtin_amdgcn_mfma_f32_16x16x32_bf16(a, bb, acc, 0, 0, 0);
    }
    #pragma unroll
    for (int r4 = 0; r4 < 4; ++r4)
      S[(lane >> 4) * 4 + r4][colbase + (lane & 15)] = acc[r4] * 0.125f;
  }
  __syncthreads();

  // ---- Phase B ----
  const float gam = fabsf(gammas[h]);
  const int jbmax_tile = (i0 + 16 + 63) >> 6;   // P cols to materialize (zero-padded)
  for (int rr = 0; rr < 4; ++rr) {
    const int r = w * 4 + rr;
    const int i = i0 + r;
    float sv[16], ev[16], tl[16];
    #pragma unroll
    for (int jb = 0; jb < 16; ++jb) { sv[jb] = -__builtin_inff(); ev[jb] = 0.f; tl[jb] = 0.f; }
    #pragma unroll
    for (int jb = 0; jb < 16; ++jb) {
      if (jb * 64 < i) {                         // uniform per-wave branch
        const int j = jb * 64 + lane;
        if (j < i) sv[jb] = S[r][j];
      }
    }
    float m1 = sv[0];
    #pragma unroll
    for (int jb = 1; jb < 16; ++jb) m1 = fmaxf(m1, sv[jb]);
    m1 = wave_max(m1);
    float zl = 0.f;
    #pragma unroll
    for (int jb = 0; jb < 16; ++jb) {
      if (jb * 64 < i) {
        const int j = jb * 64 + lane;
        ev[jb] = (j < i) ? __expf(sv[jb] - m1) : 0.f;
        zl += ev[jb];
      }
    }
    const float Z1 = wave_sum(zl);
    // inclusive suffix across lanes per jb
    #pragma unroll
    for (int jb = 0; jb < 16; ++jb) {
      if (jb * 64 < i) {
        float v = ev[jb];
        #pragma unroll
        for (int dd = 1; dd < 64; dd <<= 1) {
          const float t = __shfl_down(v, dd);
          v += (lane + dd < 64) ? t : 0.f;
        }
        tl[jb] = v;
      }
    }
    float run = 0.f;
    #pragma unroll
    for (int jb = 15; jb >= 0; --jb) {
      if (jb * 64 < i) {
        const float bs = __shfl(tl[jb], 0);      // total of this 64-col block
        tl[jb] = tl[jb] - ev[jb] + run;          // exclusive suffix
        run += bs;
      }
    }
    const float invZ1 = (i > 0) ? (1.f / Z1) : 0.f;
    float m2l = -__builtin_inff();
    #pragma unroll
    for (int jb = 0; jb < 16; ++jb) {
      if (jb * 64 < i) {
        const int j = jb * 64 + lane;
        if (j < i) {
          const float pos = (float)(i - j);
          const float dist = sqrtf(fmaxf(tl[jb] * invZ1 * pos, 0.f));
          const float eff = fmaxf(__expf(-gam * dist), 1e-5f);
          sv[jb] *= eff;
        }
        m2l = fmaxf(m2l, sv[jb]);
      }
    }
    const float m2 = wave_max(m2l);
    float z2l = 0.f;
    #pragma unroll
    for (int jb = 0; jb < 16; ++jb) {
      if (jb * 64 < i) {
        const int j = jb * 64 + lane;
        ev[jb] = (j < i) ? __expf(sv[jb] - m2) : 0.f;
        z2l += ev[jb];
      }
    }
    const float Z2 = wave_sum(z2l);
    const float sc = (Z2 > 0.f) ? (fminf(Z2, 5.f) / Z2) : 0.f;
    // write P bf16 into S row (ushort view), 16B-chunk XOR swizzle by (r&7)
    ushort_t* Pr = reinterpret_cast<ushort_t*>(&S[r][0]);
    #pragma unroll
    for (int jb = 0; jb < 16; ++jb) {
      if (jb < jbmax_tile) {
        const int c = jb * 8 + (lane >> 3);
        const int cs = c ^ (r & 7);
        Pr[cs * 8 + (lane & 7)] = f2b(ev[jb] * sc);
      }
    }
  }
  __syncthreads();

  // ---- Phase C: PV via MFMA.  wave w -> d-tile d0 = w*16 ----
  {
    const int d0 = w * 16;
    const int arow = lane & 15;
    const ushort_t* Pr = reinterpret_cast<const ushort_t*>(&S[arow][0]);
    const ushort_t* Vrow = Vt + base + (size_t)(d0 + arow) * 1024;
    const int kmax = (i0 + 16 + 31) & ~31;
    f32x4 acc = {0.f, 0.f, 0.f, 0.f};
    for (int k0 = 0; k0 < kmax; k0 += 32) {
      const int c = (k0 >> 3) + (lane >> 4);
      const int cs = c ^ (arow & 7);
      const short8 a = *reinterpret_cast<const short8*>(&Pr[cs * 8]);
      const short8 bb = *reinterpret_cast<const short8*>(&Vrow[k0 + (lane >> 4) * 8]);
      acc = __builtin_amdgcn_mfma_f32_16x16x32_bf16(a, bb, acc, 0, 0, 0);
    }
    #pragma unroll
    for (int r4 = 0; r4 < 4; ++r4) {
      const int row = (lane >> 4) * 4 + r4;
      const int i = i0 + row;
      concat[((size_t)(bi * 1024 + i)) * 1024 + h * 64 + d0 + arow] = f2b(acc[r4]);
    }
  }
}

// ---------------------------------------------------------------------------
__global__ __launch_bounds__(256) void ln_kernel(const float* __restrict__ x,
                                                 const float* __restrict__ g,
                                                 const float* __restrict__ bb,
                                                 float* __restrict__ out) {
  const int row = blockIdx.x, tid = threadIdx.x, lane = tid & 63, w = tid >> 6;
  const float4 v = reinterpret_cast<const float4*>(x + (size_t)row * 1024)[tid];
  float s = v.x + v.y + v.z + v.w;
  float q = v.x * v.x + v.y * v.y + v.z * v.z + v.w * v.w;
  s = wave_sum(s); q = wave_sum(q);
  __shared__ float ps[4], pq[4];
  if (lane == 0) { ps[w] = s; pq[w] = q; }
  __syncthreads();
  const float ts = ps[0] + ps[1] + ps[2] + ps[3];
  const float tq = pq[0] + pq[1] + pq[2] + pq[3];
  const float mu = ts * (1.f / 1024.f);
  const float inv = rsqrtf(tq * (1.f / 1024.f) - mu * mu + 1e-5f);
  const float4 gv = reinterpret_cast<const float4*>(g)[tid];
  const float4 bv = reinterpret_cast<const float4*>(bb)[tid];
  float4 o;
  o.x = (v.x - mu) * inv * gv.x + bv.x;
  o.y = (v.y - mu) * inv * gv.y + bv.y;
  o.z = (v.z - mu) * inv * gv.z + bv.z;
  o.w = (v.w - mu) * inv * gv.w + bv.w;
  reinterpret_cast<float4*>(out + (size_t)row * 1024)[tid] = o;
}

// ---------------------------------------------------------------------------
extern "C" void kernel_launch(void* const* d_in, const int* in_sizes, int n_in,
                              void* d_out, int out_size, void* d_ws, size_t ws_size,
                              hipStream_t stream) {
  (void)in_sizes; (void)n_in; (void)out_size; (void)ws_size;
  const float* query  = (const float*)d_in[0];
  const float* key    = (const float*)d_in[1];
  const float* values = (const float*)d_in[2];
  const float* Wq     = (const float*)d_in[3];
  const float* bq     = (const float*)d_in[4];
  const float* Wv     = (const float*)d_in[5];
  const float* bv     = (const float*)d_in[6];
  const float* Wo     = (const float*)d_in[7];
  const float* bo     = (const float*)d_in[8];
  const float* gammas = (const float*)d_in[9];
  const float* ln_g   = (const float*)d_in[10];
  const float* ln_b   = (const float*)d_in[11];
  float* out = (float*)d_out;

  const size_t NT = 4096ull * 1024;
  const size_t NW = 1024ull * 1024;
  char* p = (char*)d_ws;
  ushort_t* qb  = (ushort_t*)p; p += NT * 2;
  ushort_t* kb  = (ushort_t*)p; p += NT * 2;
  ushort_t* vb  = (ushort_t*)p; p += NT * 2;
  ushort_t* Wqb = (ushort_t*)p; p += NW * 2;
  ushort_t* Wvb = (ushort_t*)p; p += NW * 2;
  ushort_t* Wob = (ushort_t*)p; p += NW * 2;
  ushort_t* Qh  = (ushort_t*)p; p += NT * 2;
  ushort_t* Kh  = (ushort_t*)p; p += NT * 2;
  ushort_t* Vt  = (ushort_t*)p; p += NT * 2;
  ushort_t* concat = vb;                // free after gemm_proj
  float*    xbuf   = (float*)qb;        // spans qb+kb, free after gemm_proj

  conv_f32_bf16<<<4096, 256, 0, stream>>>(query,  qb, (int)(NT / 4));
  conv_f32_bf16<<<4096, 256, 0, stream>>>(key,    kb, (int)(NT / 4));
  conv_f32_bf16<<<4096, 256, 0, stream>>>(values, vb, (int)(NT / 4));
  conv_f32_bf16<<<1024, 256, 0, stream>>>(Wq, Wqb, (int)(NW / 4));
  conv_f32_bf16<<<1024, 256, 0, stream>>>(Wv, Wvb, (int)(NW / 4));
  conv_f32_bf16<<<1024, 256, 0, stream>>>(Wo, Wob, (int)(NW / 4));

  gemm_proj<<<dim3(8, 32, 3), 256, 0, stream>>>(qb, kb, vb, Wqb, Wvb, bq, bv, Qh, Kh, Vt);
  attn_kernel<<<dim3(64, 64), 256, 0, stream>>>(Qh, Kh, Vt, gammas, concat);
  gemm_out<<<dim3(8, 32), 256, 0, stream>>>(concat, Wob, bo, query, xbuf);
  ln_kernel<<<4096, 256, 0, stream>>>(xbuf, ln_g, ln_b, out);
}

// Round 3
// 227.733 us; speedup vs baseline: 3.6682x; 1.7943x over previous
//
#include <hip/hip_runtime.h>
#include <stdint.h>

// ---------------------------------------------------------------------------
// DTransformer layer on MI355X.  B=4, T=1024, D=1024, H=16, dk=64.
//   1. convert f32 -> bf16 (batched: 1 launch tokens, 1 launch weights)
//   2. gemm_proj: Q,K (B,H,T,64), V -> transposed (B,H,64,T)
//   3. attn: QK^T (MFMA, bf16 S in LDS) -> lane-contiguous softmax/suffix-scan
//            -> gamma effect -> softmax -> maxout -> P bf16 in place -> PV MFMA
//   4. gemm_out: x = concat@Wo^T + bo + query   5. layernorm
// ---------------------------------------------------------------------------

typedef unsigned short ushort_t;
typedef __attribute__((ext_vector_type(8))) short short8;
typedef __attribute__((ext_vector_type(8))) unsigned short u16x8;
typedef __attribute__((ext_vector_type(4))) float f32x4;
typedef __attribute__((ext_vector_type(4))) unsigned short u16x4;

#define GLB_CAST(p) ((const __attribute__((address_space(1))) void*)(p))
#define LDS_CAST(p) ((__attribute__((address_space(3))) void*)(p))

__device__ __forceinline__ float b2f(ushort_t u) {
  union { unsigned int i; float f; } x; x.i = ((unsigned int)u) << 16; return x.f;
}
__device__ __forceinline__ ushort_t f2b(float f) {
  union { float f; unsigned int i; } u; u.f = f;
  unsigned int r = u.i + 0x7FFFu + ((u.i >> 16) & 1u);   // RNE
  return (ushort_t)(r >> 16);
}
__device__ __forceinline__ float wave_max(float v) {
  #pragma unroll
  for (int d = 32; d > 0; d >>= 1) v = fmaxf(v, __shfl_xor(v, d));
  return v;
}
__device__ __forceinline__ float wave_sum(float v) {
  #pragma unroll
  for (int d = 32; d > 0; d >>= 1) v += __shfl_xor(v, d);
  return v;
}

// ---------------------------------------------------------------------------
// batched f32 -> bf16 converts (3 tensors per launch)
// ---------------------------------------------------------------------------
__global__ void conv3_f32_bf16(const float* __restrict__ s0, const float* __restrict__ s1,
                               const float* __restrict__ s2,
                               ushort_t* __restrict__ d0, ushort_t* __restrict__ d1,
                               ushort_t* __restrict__ d2, int n4) {
  const float* src = (blockIdx.y == 0) ? s0 : (blockIdx.y == 1) ? s1 : s2;
  ushort_t*    dst = (blockIdx.y == 0) ? d0 : (blockIdx.y == 1) ? d1 : d2;
  int i = blockIdx.x * blockDim.x + threadIdx.x;
  if (i < n4) {
    const float4 v = reinterpret_cast<const float4*>(src)[i];
    u16x4 o;
    o[0] = f2b(v.x); o[1] = f2b(v.y); o[2] = f2b(v.z); o[3] = f2b(v.w);
    reinterpret_cast<u16x4*>(dst)[i] = o;
  }
}

// ---------------------------------------------------------------------------
// 128x128 tile bf16 GEMM core: C[m,n] = sum_k A[m,k]*Bt[n,k]
// ---------------------------------------------------------------------------
__device__ __forceinline__ void gemm_core(const ushort_t* __restrict__ A,
                                          const ushort_t* __restrict__ Bt,
                                          int m0, int n0,
                                          ushort_t* As, ushort_t* Bs,
                                          f32x4 (&acc)[4][4]) {
  const int tid = threadIdx.x, lane = tid & 63;
  const int wid = tid >> 6;
  const int wr = (wid >> 1) * 64, wc = (wid & 1) * 64;
  for (int k0 = 0; k0 < 1024; k0 += 32) {
    #pragma unroll
    for (int it = 0; it < 2; ++it) {
      const int idx = tid * 8 + it * 2048;
      const int r = idx >> 5, kk = idx & 31;
      __builtin_amdgcn_global_load_lds(GLB_CAST(&A[(size_t)(m0 + r) * 1024 + k0 + kk]),
                                       LDS_CAST(&As[idx]), 16, 0, 0);
      __builtin_amdgcn_global_load_lds(GLB_CAST(&Bt[(size_t)(n0 + r) * 1024 + k0 + kk]),
                                       LDS_CAST(&Bs[idx]), 16, 0, 0);
    }
    __syncthreads();
    short8 af[4], bfv[4];
    #pragma unroll
    for (int m = 0; m < 4; ++m)
      af[m] = *reinterpret_cast<const short8*>(&As[(wr + m * 16 + (lane & 15)) * 32 + (lane >> 4) * 8]);
    #pragma unroll
    for (int n = 0; n < 4; ++n)
      bfv[n] = *reinterpret_cast<const short8*>(&Bs[(wc + n * 16 + (lane & 15)) * 32 + (lane >> 4) * 8]);
    #pragma unroll
    for (int m = 0; m < 4; ++m)
      #pragma unroll
      for (int n = 0; n < 4; ++n)
        acc[m][n] = __builtin_amdgcn_mfma_f32_16x16x32_bf16(af[m], bfv[n], acc[m][n], 0, 0, 0);
    __syncthreads();
  }
}

// QKV projections. z=0: Q, z=1: K -> (B,H,T,64); z=2: V -> TRANSPOSED (B,H,64,T)
__global__ __launch_bounds__(256) void gemm_proj(
    const ushort_t* __restrict__ qb, const ushort_t* __restrict__ kb, const ushort_t* __restrict__ vb,
    const ushort_t* __restrict__ Wqb, const ushort_t* __restrict__ Wvb,
    const float* __restrict__ bq, const float* __restrict__ bvv,
    ushort_t* __restrict__ Qh, ushort_t* __restrict__ Kh, ushort_t* __restrict__ Vt) {
  __shared__ ushort_t As[128 * 32], Bs[128 * 32];
  const ushort_t* A; const ushort_t* Bt; const float* bias;
  if (blockIdx.z == 0)      { A = qb; Bt = Wqb; bias = bq;  }
  else if (blockIdx.z == 1) { A = kb; Bt = Wqb; bias = bq;  }
  else                      { A = vb; Bt = Wvb; bias = bvv; }
  const int m0 = blockIdx.y * 128, n0 = blockIdx.x * 128;
  f32x4 zero = {0.f, 0.f, 0.f, 0.f};
  f32x4 acc[4][4];
  #pragma unroll
  for (int m = 0; m < 4; ++m)
    #pragma unroll
    for (int n = 0; n < 4; ++n) acc[m][n] = zero;
  gemm_core(A, Bt, m0, n0, As, Bs, acc);
  const int lane = threadIdx.x & 63, wid = threadIdx.x >> 6;
  const int wr = (wid >> 1) * 64, wc = (wid & 1) * 64;
  if (blockIdx.z == 2) {
    #pragma unroll
    for (int m = 0; m < 4; ++m)
      #pragma unroll
      for (int n = 0; n < 4; ++n) {
        const int rowb = m0 + wr + m * 16 + (lane >> 4) * 4;
        const int col  = n0 + wc + n * 16 + (lane & 15);
        u16x4 pk;
        #pragma unroll
        for (int r4 = 0; r4 < 4; ++r4) pk[r4] = f2b(acc[m][n][r4] + bias[col]);
        const int bi = rowb >> 10, t = rowb & 1023;
        *reinterpret_cast<u16x4*>(
            &Vt[((size_t)(bi * 16 + (col >> 6)) * 64 + (col & 63)) * 1024 + t]) = pk;
      }
  } else {
    ushort_t* dst = (blockIdx.z == 0) ? Qh : Kh;
    #pragma unroll
    for (int m = 0; m < 4; ++m)
      #pragma unroll
      for (int n = 0; n < 4; ++n)
        #pragma unroll
        for (int r4 = 0; r4 < 4; ++r4) {
          const int row = m0 + wr + m * 16 + (lane >> 4) * 4 + r4;
          const int col = n0 + wc + n * 16 + (lane & 15);
          const float v = acc[m][n][r4] + bias[col];
          const int bi = row >> 10, t = row & 1023, h = col >> 6, dd = col & 63;
          dst[((size_t)(bi * 16 + h) * 1024 + t) * 64 + dd] = f2b(v);
        }
  }
}

// Output projection: x = concat@Wo^T + bo + query   (f32)
__global__ __launch_bounds__(256) void gemm_out(
    const ushort_t* __restrict__ A, const ushort_t* __restrict__ Bt,
    const float* __restrict__ bias, const float* __restrict__ resid,
    float* __restrict__ dstF) {
  __shared__ ushort_t As[128 * 32], Bs[128 * 32];
  const int m0 = blockIdx.y * 128, n0 = blockIdx.x * 128;
  f32x4 zero = {0.f, 0.f, 0.f, 0.f};
  f32x4 acc[4][4];
  #pragma unroll
  for (int m = 0; m < 4; ++m)
    #pragma unroll
    for (int n = 0; n < 4; ++n) acc[m][n] = zero;
  gemm_core(A, Bt, m0, n0, As, Bs, acc);
  const int lane = threadIdx.x & 63, wid = threadIdx.x >> 6;
  const int wr = (wid >> 1) * 64, wc = (wid & 1) * 64;
  #pragma unroll
  for (int m = 0; m < 4; ++m)
    #pragma unroll
    for (int n = 0; n < 4; ++n)
      #pragma unroll
      for (int r4 = 0; r4 < 4; ++r4) {
        const int row = m0 + wr + m * 16 + (lane >> 4) * 4 + r4;
        const int col = n0 + wc + n * 16 + (lane & 15);
        const size_t o = (size_t)row * 1024 + col;
        dstF[o] = acc[m][n][r4] + bias[col] + resid[o];
      }
}

// ---------------------------------------------------------------------------
// Attention.  grid = (T/16, B*H), 256 threads (4 waves).
// S stored bf16 in LDS, row stride 1032 ushorts (2064 B), 16B chunks placed at
// q(c) = c ^ ((c>>3)&7)  (c = column>>3).  Lane L owns columns 16L..16L+15.
// Phase A: QK^T/8 via MFMA -> bf16 S.   Phase B: per wave 4 rows, all
// reductions in-register + 1 wave scan + 3 wave reduces; P bf16 in place.
// Phase C: PV via MFMA (Vt from global).
// ---------------------------------------------------------------------------
__global__ __launch_bounds__(256, 4) void attn_kernel(
    const ushort_t* __restrict__ Qh, const ushort_t* __restrict__ Kh,
    const ushort_t* __restrict__ Vt, const float* __restrict__ gammas,
    ushort_t* __restrict__ concat) {
  __shared__ __align__(16) ushort_t Sb[16 * 1032];
  __shared__ __align__(16) ushort_t Qs[16 * 72];     // padded stride 72
  const int tid = threadIdx.x, lane = tid & 63, w = tid >> 6;
  const int bh = blockIdx.y, bi = bh >> 4, h = bh & 15;
  const int i0 = blockIdx.x * 16;
  const size_t base = (size_t)bh * (1024 * 64);

  { // stage Q tile (16 rows x 64)
    const int r = tid >> 4, d = (tid & 15) * 4;
    *reinterpret_cast<u16x4*>(&Qs[r * 72 + d]) =
        *reinterpret_cast<const u16x4*>(&Qh[base + (size_t)(i0 + r) * 64 + d]);
  }
  __syncthreads();

  // ---- Phase A: scores -> bf16 S ----
  const int upper = i0 + 16;
  for (int nt = 0; nt < 16; ++nt) {
    const int colbase = (nt * 4 + w) * 16;
    if (colbase >= upper) break;
    f32x4 acc = {0.f, 0.f, 0.f, 0.f};
    #pragma unroll
    for (int kt = 0; kt < 2; ++kt) {
      const short8 a = *reinterpret_cast<const short8*>(
          &Qs[(lane & 15) * 72 + kt * 32 + (lane >> 4) * 8]);
      const short8 bb = *reinterpret_cast<const short8*>(
          &Kh[base + (size_t)(colbase + (lane & 15)) * 64 + kt * 32 + (lane >> 4) * 8]);
      acc = __builtin_amdgcn_mfma_f32_16x16x32_bf16(a, bb, acc, 0, 0, 0);
    }
    const int j = colbase + (lane & 15);
    const int cq = (j >> 3) ^ ((j >> 6) & 7);
    const int ub = cq * 8 + (j & 7);
    #pragma unroll
    for (int r4 = 0; r4 < 4; ++r4) {
      const int rf = (lane >> 4) * 4 + r4;
      Sb[rf * 1032 + ub] = f2b(acc[r4] * 0.125f);
    }
  }
  __syncthreads();

  // ---- Phase B: per wave, 4 rows; lane L owns columns 16L..16L+15 ----
  const float gam = fabsf(gammas[h]);
  const int q0 = (2 * lane) ^ ((lane >> 2) & 7);
  const int q1 = (2 * lane + 1) ^ ((lane >> 2) & 7);
  for (int rr = 0; rr < 4; ++rr) {
    const int r = w * 4 + rr;
    const int i = i0 + r;
    ushort_t* Row = &Sb[r * 1032];
    const u16x8 raw0 = *reinterpret_cast<const u16x8*>(&Row[q0 * 8]);
    const u16x8 raw1 = *reinterpret_cast<const u16x8*>(&Row[q1 * 8]);
    const int nact = min(max(i - 16 * lane, 0), 16);
    float s[16], ev[16], tl[16];
    #pragma unroll
    for (int e = 0; e < 8; ++e) { s[e] = b2f(raw0[e]); s[8 + e] = b2f(raw1[e]); }
    // first max
    float m1 = -__builtin_inff();
    #pragma unroll
    for (int e = 0; e < 16; ++e) if (e < nact) m1 = fmaxf(m1, s[e]);
    m1 = wave_max(m1);
    // exp + in-lane suffix
    #pragma unroll
    for (int e = 0; e < 16; ++e) ev[e] = (e < nact) ? __expf(s[e] - m1) : 0.f;
    float run = 0.f;
    #pragma unroll
    for (int e = 15; e >= 0; --e) { tl[e] = run; run += ev[e]; }
    // wave-level inclusive suffix of lane totals
    float v = run;
    #pragma unroll
    for (int d = 1; d < 64; d <<= 1) {
      const float t = __shfl_down(v, d);
      v += (lane + d < 64) ? t : 0.f;
    }
    const float Z1 = __shfl(v, 0);
    const float excl = v - run;
    const float invZ1 = (i > 0) ? (1.f / Z1) : 0.f;
    // gamma distance effect + second max
    float m2 = -__builtin_inff();
    #pragma unroll
    for (int e = 0; e < 16; ++e) {
      if (e < nact) {
        const float pos = (float)(i - (16 * lane + e));
        const float dist = sqrtf(fmaxf((tl[e] + excl) * invZ1 * pos, 0.f));
        const float eff = fmaxf(__expf(-gam * dist), 1e-5f);
        s[e] *= eff;
        m2 = fmaxf(m2, s[e]);
      }
    }
    m2 = wave_max(m2);
    float z2 = 0.f;
    #pragma unroll
    for (int e = 0; e < 16; ++e) {
      ev[e] = (e < nact) ? __expf(s[e] - m2) : 0.f;
      z2 += ev[e];
    }
    const float Z2 = wave_sum(z2);
    const float sc = (Z2 > 0.f) ? (fminf(Z2, 5.f) / Z2) : 0.f;
    u16x8 o0, o1;
    #pragma unroll
    for (int e = 0; e < 8; ++e) { o0[e] = f2b(ev[e] * sc); o1[e] = f2b(ev[8 + e] * sc); }
    *reinterpret_cast<u16x8*>(&Row[q0 * 8]) = o0;
    *reinterpret_cast<u16x8*>(&Row[q1 * 8]) = o1;
  }
  __syncthreads();

  // ---- Phase C: PV via MFMA.  wave w -> d-tile d0 = w*16 ----
  {
    const int d0 = w * 16;
    const int arow = lane & 15;
    const ushort_t* Prow = &Sb[arow * 1032];
    const ushort_t* Vrow = Vt + base + (size_t)(d0 + arow) * 1024;
    const int kmax = (i0 + 16 + 31) & ~31;
    f32x4 acc = {0.f, 0.f, 0.f, 0.f};
    for (int k0 = 0; k0 < kmax; k0 += 32) {
      const int c = (k0 >> 3) + (lane >> 4);
      const int cq = c ^ ((c >> 3) & 7);
      const short8 a = *reinterpret_cast<const short8*>(&Prow[cq * 8]);
      const short8 bb = *reinterpret_cast<const short8*>(&Vrow[k0 + (lane >> 4) * 8]);
      acc = __builtin_amdgcn_mfma_f32_16x16x32_bf16(a, bb, acc, 0, 0, 0);
    }
    #pragma unroll
    for (int r4 = 0; r4 < 4; ++r4) {
      const int row = (lane >> 4) * 4 + r4;
      const int i = i0 + row;
      concat[((size_t)(bi * 1024 + i)) * 1024 + h * 64 + d0 + arow] = f2b(acc[r4]);
    }
  }
}

// ---------------------------------------------------------------------------
__global__ __launch_bounds__(256) void ln_kernel(const float* __restrict__ x,
                                                 const float* __restrict__ g,
                                                 const float* __restrict__ bb,
                                                 float* __restrict__ out) {
  const int row = blockIdx.x, tid = threadIdx.x, lane = tid & 63, w = tid >> 6;
  const float4 v = reinterpret_cast<const float4*>(x + (size_t)row * 1024)[tid];
  float s = v.x + v.y + v.z + v.w;
  float q = v.x * v.x + v.y * v.y + v.z * v.z + v.w * v.w;
  s = wave_sum(s); q = wave_sum(q);
  __shared__ float ps[4], pq[4];
  if (lane == 0) { ps[w] = s; pq[w] = q; }
  __syncthreads();
  const float ts = ps[0] + ps[1] + ps[2] + ps[3];
  const float tq = pq[0] + pq[1] + pq[2] + pq[3];
  const float mu = ts * (1.f / 1024.f);
  const float inv = rsqrtf(tq * (1.f / 1024.f) - mu * mu + 1e-5f);
  const float4 gv = reinterpret_cast<const float4*>(g)[tid];
  const float4 bv = reinterpret_cast<const float4*>(bb)[tid];
  float4 o;
  o.x = (v.x - mu) * inv * gv.x + bv.x;
  o.y = (v.y - mu) * inv * gv.y + bv.y;
  o.z = (v.z - mu) * inv * gv.z + bv.z;
  o.w = (v.w - mu) * inv * gv.w + bv.w;
  reinterpret_cast<float4*>(out + (size_t)row * 1024)[tid] = o;
}

// ---------------------------------------------------------------------------
extern "C" void kernel_launch(void* const* d_in, const int* in_sizes, int n_in,
                              void* d_out, int out_size, void* d_ws, size_t ws_size,
                              hipStream_t stream) {
  (void)in_sizes; (void)n_in; (void)out_size; (void)ws_size;
  const float* query  = (const float*)d_in[0];
  const float* key    = (const float*)d_in[1];
  const float* values = (const float*)d_in[2];
  const float* Wq     = (const float*)d_in[3];
  const float* bq     = (const float*)d_in[4];
  const float* Wv     = (const float*)d_in[5];
  const float* bv     = (const float*)d_in[6];
  const float* Wo     = (const float*)d_in[7];
  const float* bo     = (const float*)d_in[8];
  const float* gammas = (const float*)d_in[9];
  const float* ln_g   = (const float*)d_in[10];
  const float* ln_b   = (const float*)d_in[11];
  float* out = (float*)d_out;

  const size_t NT = 4096ull * 1024;
  const size_t NW = 1024ull * 1024;
  char* p = (char*)d_ws;
  ushort_t* qb  = (ushort_t*)p; p += NT * 2;
  ushort_t* kb  = (ushort_t*)p; p += NT * 2;
  ushort_t* vb  = (ushort_t*)p; p += NT * 2;
  ushort_t* Wqb = (ushort_t*)p; p += NW * 2;
  ushort_t* Wvb = (ushort_t*)p; p += NW * 2;
  ushort_t* Wob = (ushort_t*)p; p += NW * 2;
  ushort_t* Qh  = (ushort_t*)p; p += NT * 2;
  ushort_t* Kh  = (ushort_t*)p; p += NT * 2;
  ushort_t* Vt  = (ushort_t*)p; p += NT * 2;
  ushort_t* concat = vb;                // free after gemm_proj
  float*    xbuf   = (float*)qb;        // spans qb+kb, free after gemm_proj

  conv3_f32_bf16<<<dim3(4096, 3), 256, 0, stream>>>(query, key, values, qb, kb, vb, (int)(NT / 4));
  conv3_f32_bf16<<<dim3(1024, 3), 256, 0, stream>>>(Wq, Wv, Wo, Wqb, Wvb, Wob, (int)(NW / 4));

  gemm_proj<<<dim3(8, 32, 3), 256, 0, stream>>>(qb, kb, vb, Wqb, Wvb, bq, bv, Qh, Kh, Vt);
  attn_kernel<<<dim3(64, 64), 256, 0, stream>>>(Qh, Kh, Vt, gammas, concat);
  gemm_out<<<dim3(8, 32), 256, 0, stream>>>(concat, Wob, bo, query, xbuf);
  ln_kernel<<<4096, 256, 0, stream>>>(xbuf, ln_g, ln_b, out);
}

// Round 4
// 202.482 us; speedup vs baseline: 4.1257x; 1.1247x over previous
//
#include <hip/hip_runtime.h>
#include <hip/hip_bf16.h>
#include <stdint.h>

// ---------------------------------------------------------------------------
// DTransformer layer on MI355X.  B=4, T=1024, D=1024, H=16, dk=64.
//   1. conv f32 -> bf16 (single batched launch)
//   2. gemm_proj: Q,K (B,H,T,64), V -> transposed (B,H,64,T)
//   3. attn: QK^T (MFMA, bf16 S in LDS) -> causally-tiered lane-contiguous
//      softmax/suffix-scan (exp2 domain) -> gamma effect -> softmax -> maxout
//      -> P bf16 in place -> PV via MFMA
//   4. gemm_out: x = concat@Wo^T + bo + query   5. layernorm
// ---------------------------------------------------------------------------

typedef unsigned short ushort_t;
typedef __attribute__((ext_vector_type(8))) short short8;
typedef __attribute__((ext_vector_type(8))) unsigned short u16x8;
typedef __attribute__((ext_vector_type(4))) float f32x4;
typedef __attribute__((ext_vector_type(4))) unsigned short u16x4;

#define GLB_CAST(p) ((const __attribute__((address_space(1))) void*)(p))
#define LDS_CAST(p) ((__attribute__((address_space(3))) void*)(p))

#if __has_builtin(__builtin_amdgcn_exp2f)
#define EXP2F(x) __builtin_amdgcn_exp2f(x)
#else
#define EXP2F(x) exp2f(x)
#endif

#define LOG2E 1.44269504f

__device__ __forceinline__ float b2f(ushort_t u) {
  union { unsigned int i; float f; } x; x.i = ((unsigned int)u) << 16; return x.f;
}
__device__ __forceinline__ ushort_t f2b(float f) {   // RNE via hw convert
  __hip_bfloat16 h = __float2bfloat16(f);
  return *reinterpret_cast<ushort_t*>(&h);
}
__device__ __forceinline__ float wave_max(float v) {
  #pragma unroll
  for (int d = 32; d > 0; d >>= 1) v = fmaxf(v, __shfl_xor(v, d));
  return v;
}
__device__ __forceinline__ float wave_sum(float v) {
  #pragma unroll
  for (int d = 32; d > 0; d >>= 1) v += __shfl_xor(v, d);
  return v;
}

// ---------------------------------------------------------------------------
// batched f32 -> bf16 converts: y 0..2 tokens (4096 blk), y 3..5 weights (1024)
// ---------------------------------------------------------------------------
__global__ void conv6_f32_bf16(const float* __restrict__ s0, const float* __restrict__ s1,
                               const float* __restrict__ s2, const float* __restrict__ s3,
                               const float* __restrict__ s4, const float* __restrict__ s5,
                               ushort_t* __restrict__ d0, ushort_t* __restrict__ d1,
                               ushort_t* __restrict__ d2, ushort_t* __restrict__ d3,
                               ushort_t* __restrict__ d4, ushort_t* __restrict__ d5,
                               int n4tok, int n4w) {
  const int y = blockIdx.y;
  const float* srcs[6] = {s0, s1, s2, s3, s4, s5};
  ushort_t*    dsts[6] = {d0, d1, d2, d3, d4, d5};
  const int n4 = (y < 3) ? n4tok : n4w;
  int i = blockIdx.x * blockDim.x + threadIdx.x;
  if (i < n4) {
    const float4 v = reinterpret_cast<const float4*>(srcs[y])[i];
    u16x4 o;
    o[0] = f2b(v.x); o[1] = f2b(v.y); o[2] = f2b(v.z); o[3] = f2b(v.w);
    reinterpret_cast<u16x4*>(dsts[y])[i] = o;
  }
}

// ---------------------------------------------------------------------------
// 128x128 tile bf16 GEMM core: C[m,n] = sum_k A[m,k]*Bt[n,k]
// ---------------------------------------------------------------------------
__device__ __forceinline__ void gemm_core(const ushort_t* __restrict__ A,
                                          const ushort_t* __restrict__ Bt,
                                          int m0, int n0,
                                          ushort_t* As, ushort_t* Bs,
                                          f32x4 (&acc)[4][4]) {
  const int tid = threadIdx.x, lane = tid & 63;
  const int wid = tid >> 6;
  const int wr = (wid >> 1) * 64, wc = (wid & 1) * 64;
  for (int k0 = 0; k0 < 1024; k0 += 32) {
    #pragma unroll
    for (int it = 0; it < 2; ++it) {
      const int idx = tid * 8 + it * 2048;
      const int r = idx >> 5, kk = idx & 31;
      __builtin_amdgcn_global_load_lds(GLB_CAST(&A[(size_t)(m0 + r) * 1024 + k0 + kk]),
                                       LDS_CAST(&As[idx]), 16, 0, 0);
      __builtin_amdgcn_global_load_lds(GLB_CAST(&Bt[(size_t)(n0 + r) * 1024 + k0 + kk]),
                                       LDS_CAST(&Bs[idx]), 16, 0, 0);
    }
    __syncthreads();
    short8 af[4], bfv[4];
    #pragma unroll
    for (int m = 0; m < 4; ++m)
      af[m] = *reinterpret_cast<const short8*>(&As[(wr + m * 16 + (lane & 15)) * 32 + (lane >> 4) * 8]);
    #pragma unroll
    for (int n = 0; n < 4; ++n)
      bfv[n] = *reinterpret_cast<const short8*>(&Bs[(wc + n * 16 + (lane & 15)) * 32 + (lane >> 4) * 8]);
    #pragma unroll
    for (int m = 0; m < 4; ++m)
      #pragma unroll
      for (int n = 0; n < 4; ++n)
        acc[m][n] = __builtin_amdgcn_mfma_f32_16x16x32_bf16(af[m], bfv[n], acc[m][n], 0, 0, 0);
    __syncthreads();
  }
}

// QKV projections. z=0: Q, z=1: K -> (B,H,T,64); z=2: V -> TRANSPOSED (B,H,64,T)
__global__ __launch_bounds__(256) void gemm_proj(
    const ushort_t* __restrict__ qb, const ushort_t* __restrict__ kb, const ushort_t* __restrict__ vb,
    const ushort_t* __restrict__ Wqb, const ushort_t* __restrict__ Wvb,
    const float* __restrict__ bq, const float* __restrict__ bvv,
    ushort_t* __restrict__ Qh, ushort_t* __restrict__ Kh, ushort_t* __restrict__ Vt) {
  __shared__ ushort_t As[128 * 32], Bs[128 * 32];
  const ushort_t* A; const ushort_t* Bt; const float* bias;
  if (blockIdx.z == 0)      { A = qb; Bt = Wqb; bias = bq;  }
  else if (blockIdx.z == 1) { A = kb; Bt = Wqb; bias = bq;  }
  else                      { A = vb; Bt = Wvb; bias = bvv; }
  const int m0 = blockIdx.y * 128, n0 = blockIdx.x * 128;
  f32x4 zero = {0.f, 0.f, 0.f, 0.f};
  f32x4 acc[4][4];
  #pragma unroll
  for (int m = 0; m < 4; ++m)
    #pragma unroll
    for (int n = 0; n < 4; ++n) acc[m][n] = zero;
  gemm_core(A, Bt, m0, n0, As, Bs, acc);
  const int lane = threadIdx.x & 63, wid = threadIdx.x >> 6;
  const int wr = (wid >> 1) * 64, wc = (wid & 1) * 64;
  if (blockIdx.z == 2) {
    #pragma unroll
    for (int m = 0; m < 4; ++m)
      #pragma unroll
      for (int n = 0; n < 4; ++n) {
        const int rowb = m0 + wr + m * 16 + (lane >> 4) * 4;
        const int col  = n0 + wc + n * 16 + (lane & 15);
        u16x4 pk;
        #pragma unroll
        for (int r4 = 0; r4 < 4; ++r4) pk[r4] = f2b(acc[m][n][r4] + bias[col]);
        const int bi = rowb >> 10, t = rowb & 1023;
        *reinterpret_cast<u16x4*>(
            &Vt[((size_t)(bi * 16 + (col >> 6)) * 64 + (col & 63)) * 1024 + t]) = pk;
      }
  } else {
    ushort_t* dst = (blockIdx.z == 0) ? Qh : Kh;
    #pragma unroll
    for (int m = 0; m < 4; ++m)
      #pragma unroll
      for (int n = 0; n < 4; ++n)
        #pragma unroll
        for (int r4 = 0; r4 < 4; ++r4) {
          const int row = m0 + wr + m * 16 + (lane >> 4) * 4 + r4;
          const int col = n0 + wc + n * 16 + (lane & 15);
          const float v = acc[m][n][r4] + bias[col];
          const int bi = row >> 10, t = row & 1023, h = col >> 6, dd = col & 63;
          dst[((size_t)(bi * 16 + h) * 1024 + t) * 64 + dd] = f2b(v);
        }
  }
}

// Output projection: x = concat@Wo^T + bo + query   (f32)
__global__ __launch_bounds__(256) void gemm_out(
    const ushort_t* __restrict__ A, const ushort_t* __restrict__ Bt,
    const float* __restrict__ bias, const float* __restrict__ resid,
    float* __restrict__ dstF) {
  __shared__ ushort_t As[128 * 32], Bs[128 * 32];
  const int m0 = blockIdx.y * 128, n0 = blockIdx.x * 128;
  f32x4 zero = {0.f, 0.f, 0.f, 0.f};
  f32x4 acc[4][4];
  #pragma unroll
  for (int m = 0; m < 4; ++m)
    #pragma unroll
    for (int n = 0; n < 4; ++n) acc[m][n] = zero;
  gemm_core(A, Bt, m0, n0, As, Bs, acc);
  const int lane = threadIdx.x & 63, wid = threadIdx.x >> 6;
  const int wr = (wid >> 1) * 64, wc = (wid & 1) * 64;
  #pragma unroll
  for (int m = 0; m < 4; ++m)
    #pragma unroll
    for (int n = 0; n < 4; ++n)
      #pragma unroll
      for (int r4 = 0; r4 < 4; ++r4) {
        const int row = m0 + wr + m * 16 + (lane >> 4) * 4 + r4;
        const int col = n0 + wc + n * 16 + (lane & 15);
        const size_t o = (size_t)row * 1024 + col;
        dstF[o] = acc[m][n][r4] + bias[col] + resid[o];
      }
}

// ---------------------------------------------------------------------------
// Phase B worker, CH columns per lane (lane L owns cols [CH*L, CH*(L+1))).
// Scores in LDS are bf16, swizzled: col j at ushort index
//   u(j) = ((j>>3) ^ ((j>>6)&7))*8 + (j&7),  row stride 1032.
// All exps in exp2 domain (scores pre-scaled by log2e).
// ---------------------------------------------------------------------------
template<int CH>
__device__ __forceinline__ void phase_b(ushort_t* __restrict__ Sb, const int i0,
                                        const int w, const int lane, const float gamx) {
  const int c0 = CH * lane;
  int idxA = 0, idxB = 0;
  if constexpr (CH == 16) {
    const int ca = 2 * lane, cb = 2 * lane + 1;
    idxA = (ca ^ ((ca >> 3) & 7)) << 3;
    idxB = (cb ^ ((cb >> 3) & 7)) << 3;
  } else {
    const int c = c0 >> 3;
    idxA = ((c ^ ((c >> 3) & 7)) << 3) + (c0 & 7);
  }
  for (int rr = 0; rr < 4; ++rr) {
    const int r = w * 4 + rr;
    const int i = i0 + r;
    ushort_t* __restrict__ Row = &Sb[r * 1032];
    if (i == 0) {                       // fully masked row -> P = 0
      #pragma unroll
      for (int e = 0; e < CH; ++e) {
        if constexpr (CH == 16) Row[(e < 8) ? (idxA + e) : (idxB + e - 8)] = 0;
        else                    Row[idxA + e] = 0;
      }
      continue;
    }
    float s[CH];
    if constexpr (CH == 16) {
      const u16x8 ra = *reinterpret_cast<const u16x8*>(&Row[idxA]);
      const u16x8 rb = *reinterpret_cast<const u16x8*>(&Row[idxB]);
      #pragma unroll
      for (int e = 0; e < 8; ++e) { s[e] = b2f(ra[e]); s[8 + e] = b2f(rb[e]); }
    } else if constexpr (CH == 8) {
      const u16x8 ra = *reinterpret_cast<const u16x8*>(&Row[idxA]);
      #pragma unroll
      for (int e = 0; e < 8; ++e) s[e] = b2f(ra[e]);
    } else if constexpr (CH == 4) {
      const u16x4 ra = *reinterpret_cast<const u16x4*>(&Row[idxA]);
      #pragma unroll
      for (int e = 0; e < 4; ++e) s[e] = b2f(ra[e]);
    } else if constexpr (CH == 2) {
      s[0] = b2f(Row[idxA]); s[1] = b2f(Row[idxA + 1]);
    } else {
      s[0] = b2f(Row[idxA]);
    }
    const int nact = min(max(i - c0, 0), CH);
    #pragma unroll
    for (int e = 0; e < CH; ++e)
      s[e] = (e < nact) ? s[e] * LOG2E : -__builtin_inff();
    // first max (wave max finite since i > 0)
    float m1 = s[0];
    #pragma unroll
    for (int e = 1; e < CH; ++e) m1 = fmaxf(m1, s[e]);
    m1 = wave_max(m1);
    // exp + in-lane exclusive suffix
    float ev[CH], tl[CH];
    float run = 0.f;
    #pragma unroll
    for (int e = CH - 1; e >= 0; --e) {
      ev[e] = EXP2F(s[e] - m1);         // exact 0 for masked
      tl[e] = run; run += ev[e];
    }
    // wave-level suffix of lane totals
    float v = run;
    #pragma unroll
    for (int d = 1; d < 64; d <<= 1) {
      const float t = __shfl_down(v, d);
      v += (lane + d < 64) ? t : 0.f;
    }
    const float Z1 = __shfl(v, 0);
    const float excl = v - run;
    // gamma distance effect + second max
    const float g2 = -gamx * sqrtf(1.f / Z1);
    const float posb = (float)(i - c0);
    float m2 = -__builtin_inff();
    #pragma unroll
    for (int e = 0; e < CH; ++e) {
      const float t = fmaxf((tl[e] + excl) * (posb - (float)e), 0.f);
      const float eff = fmaxf(EXP2F(g2 * sqrtf(t)), 1e-5f);
      s[e] *= eff;                      // -inf stays -inf (eff in (0,1])
      m2 = fmaxf(m2, s[e]);
    }
    m2 = wave_max(m2);
    float z2 = 0.f;
    #pragma unroll
    for (int e = 0; e < CH; ++e) { ev[e] = EXP2F(s[e] - m2); z2 += ev[e]; }
    const float Z2 = wave_sum(z2);
    const float sc = fminf(Z2, 5.f) / Z2;   // maxout (max p = 1/Z2)
    if constexpr (CH == 16) {
      u16x8 oa, ob;
      #pragma unroll
      for (int e = 0; e < 8; ++e) { oa[e] = f2b(ev[e] * sc); ob[e] = f2b(ev[8 + e] * sc); }
      *reinterpret_cast<u16x8*>(&Row[idxA]) = oa;
      *reinterpret_cast<u16x8*>(&Row[idxB]) = ob;
    } else if constexpr (CH == 8) {
      u16x8 oa;
      #pragma unroll
      for (int e = 0; e < 8; ++e) oa[e] = f2b(ev[e] * sc);
      *reinterpret_cast<u16x8*>(&Row[idxA]) = oa;
    } else if constexpr (CH == 4) {
      u16x4 oa;
      #pragma unroll
      for (int e = 0; e < 4; ++e) oa[e] = f2b(ev[e] * sc);
      *reinterpret_cast<u16x4*>(&Row[idxA]) = oa;
    } else if constexpr (CH == 2) {
      Row[idxA] = f2b(ev[0] * sc); Row[idxA + 1] = f2b(ev[1] * sc);
    } else {
      Row[idxA] = f2b(ev[0] * sc);
    }
  }
}

// ---------------------------------------------------------------------------
// Attention.  grid = (T/16, B*H), 256 threads (4 waves).
// ---------------------------------------------------------------------------
__global__ __launch_bounds__(256, 4) void attn_kernel(
    const ushort_t* __restrict__ Qh, const ushort_t* __restrict__ Kh,
    const ushort_t* __restrict__ Vt, const float* __restrict__ gammas,
    ushort_t* __restrict__ concat) {
  __shared__ __align__(16) ushort_t Sb[16 * 1032];
  __shared__ __align__(16) ushort_t Qs[16 * 72];     // padded stride 72
  const int tid = threadIdx.x, lane = tid & 63, w = tid >> 6;
  const int bh = blockIdx.y, bi = bh >> 4, h = bh & 15;
  const int i0 = blockIdx.x * 16;
  const size_t base = (size_t)bh * (1024 * 64);

  { // stage Q tile (16 rows x 64)
    const int r = tid >> 4, d = (tid & 15) * 4;
    *reinterpret_cast<u16x4*>(&Qs[r * 72 + d]) =
        *reinterpret_cast<const u16x4*>(&Qh[base + (size_t)(i0 + r) * 64 + d]);
  }
  __syncthreads();

  // ---- Phase A: scores -> bf16 S (swizzled) ----
  const int upper = i0 + 16;
  for (int nt = 0; nt < 16; ++nt) {
    const int colbase = (nt * 4 + w) * 16;
    if (colbase >= upper) break;
    f32x4 acc = {0.f, 0.f, 0.f, 0.f};
    #pragma unroll
    for (int kt = 0; kt < 2; ++kt) {
      const short8 a = *reinterpret_cast<const short8*>(
          &Qs[(lane & 15) * 72 + kt * 32 + (lane >> 4) * 8]);
      const short8 bb = *reinterpret_cast<const short8*>(
          &Kh[base + (size_t)(colbase + (lane & 15)) * 64 + kt * 32 + (lane >> 4) * 8]);
      acc = __builtin_amdgcn_mfma_f32_16x16x32_bf16(a, bb, acc, 0, 0, 0);
    }
    const int j = colbase + (lane & 15);
    const int cq = (j >> 3) ^ ((j >> 6) & 7);
    const int ub = cq * 8 + (j & 7);
    #pragma unroll
    for (int r4 = 0; r4 < 4; ++r4) {
      const int rf = (lane >> 4) * 4 + r4;
      Sb[rf * 1032 + ub] = f2b(acc[r4] * 0.125f);
    }
  }
  __syncthreads();

  // ---- Phase B: causally tiered ----
  const float gamx = fabsf(gammas[h]) * LOG2E;
  const int chp = (upper + 63) >> 6;        // cols/lane needed (block-uniform)
  if (chp == 1)      phase_b<1>(Sb, i0, w, lane, gamx);
  else if (chp == 2) phase_b<2>(Sb, i0, w, lane, gamx);
  else if (chp <= 4) phase_b<4>(Sb, i0, w, lane, gamx);
  else if (chp <= 8) phase_b<8>(Sb, i0, w, lane, gamx);
  else               phase_b<16>(Sb, i0, w, lane, gamx);
  __syncthreads();

  // ---- Phase C: PV via MFMA.  wave w -> d-tile d0 = w*16 ----
  {
    const int d0 = w * 16;
    const int arow = lane & 15;
    const ushort_t* Prow = &Sb[arow * 1032];
    const ushort_t* Vrow = Vt + base + (size_t)(d0 + arow) * 1024;
    const int kmax = (upper + 31) & ~31;
    f32x4 acc = {0.f, 0.f, 0.f, 0.f};
    for (int k0 = 0; k0 < kmax; k0 += 32) {
      const int c = (k0 >> 3) + (lane >> 4);
      const int cq = c ^ ((c >> 3) & 7);
      const short8 a = *reinterpret_cast<const short8*>(&Prow[cq * 8]);
      const short8 bb = *reinterpret_cast<const short8*>(&Vrow[k0 + (lane >> 4) * 8]);
      acc = __builtin_amdgcn_mfma_f32_16x16x32_bf16(a, bb, acc, 0, 0, 0);
    }
    #pragma unroll
    for (int r4 = 0; r4 < 4; ++r4) {
      const int row = (lane >> 4) * 4 + r4;
      const int i = i0 + row;
      concat[((size_t)(bi * 1024 + i)) * 1024 + h * 64 + d0 + arow] = f2b(acc[r4]);
    }
  }
}

// ---------------------------------------------------------------------------
__global__ __launch_bounds__(256) void ln_kernel(const float* __restrict__ x,
                                                 const float* __restrict__ g,
                                                 const float* __restrict__ bb,
                                                 float* __restrict__ out) {
  const int row = blockIdx.x, tid = threadIdx.x, lane = tid & 63, w = tid >> 6;
  const float4 v = reinterpret_cast<const float4*>(x + (size_t)row * 1024)[tid];
  float s = v.x + v.y + v.z + v.w;
  float q = v.x * v.x + v.y * v.y + v.z * v.z + v.w * v.w;
  s = wave_sum(s); q = wave_sum(q);
  __shared__ float ps[4], pq[4];
  if (lane == 0) { ps[w] = s; pq[w] = q; }
  __syncthreads();
  const float ts = ps[0] + ps[1] + ps[2] + ps[3];
  const float tq = pq[0] + pq[1] + pq[2] + pq[3];
  const float mu = ts * (1.f / 1024.f);
  const float inv = rsqrtf(tq * (1.f / 1024.f) - mu * mu + 1e-5f);
  const float4 gv = reinterpret_cast<const float4*>(g)[tid];
  const float4 bv = reinterpret_cast<const float4*>(bb)[tid];
  float4 o;
  o.x = (v.x - mu) * inv * gv.x + bv.x;
  o.y = (v.y - mu) * inv * gv.y + bv.y;
  o.z = (v.z - mu) * inv * gv.z + bv.z;
  o.w = (v.w - mu) * inv * gv.w + bv.w;
  reinterpret_cast<float4*>(out + (size_t)row * 1024)[tid] = o;
}

// ---------------------------------------------------------------------------
extern "C" void kernel_launch(void* const* d_in, const int* in_sizes, int n_in,
                              void* d_out, int out_size, void* d_ws, size_t ws_size,
                              hipStream_t stream) {
  (void)in_sizes; (void)n_in; (void)out_size; (void)ws_size;
  const float* query  = (const float*)d_in[0];
  const float* key    = (const float*)d_in[1];
  const float* values = (const float*)d_in[2];
  const float* Wq     = (const float*)d_in[3];
  const float* bq     = (const float*)d_in[4];
  const float* Wv     = (const float*)d_in[5];
  const float* bv     = (const float*)d_in[6];
  const float* Wo     = (const float*)d_in[7];
  const float* bo     = (const float*)d_in[8];
  const float* gammas = (const float*)d_in[9];
  const float* ln_g   = (const float*)d_in[10];
  const float* ln_b   = (const float*)d_in[11];
  float* out = (float*)d_out;

  const size_t NT = 4096ull * 1024;
  const size_t NW = 1024ull * 1024;
  char* p = (char*)d_ws;
  ushort_t* qb  = (ushort_t*)p; p += NT * 2;
  ushort_t* kb  = (ushort_t*)p; p += NT * 2;
  ushort_t* vb  = (ushort_t*)p; p += NT * 2;
  ushort_t* Wqb = (ushort_t*)p; p += NW * 2;
  ushort_t* Wvb = (ushort_t*)p; p += NW * 2;
  ushort_t* Wob = (ushort_t*)p; p += NW * 2;
  ushort_t* Qh  = (ushort_t*)p; p += NT * 2;
  ushort_t* Kh  = (ushort_t*)p; p += NT * 2;
  ushort_t* Vt  = (ushort_t*)p; p += NT * 2;
  ushort_t* concat = vb;                // free after gemm_proj
  float*    xbuf   = (float*)qb;        // spans qb+kb, free after gemm_proj

  conv6_f32_bf16<<<dim3(4096, 6), 256, 0, stream>>>(
      query, key, values, Wq, Wv, Wo, qb, kb, vb, Wqb, Wvb, Wob,
      (int)(NT / 4), (int)(NW / 4));

  gemm_proj<<<dim3(8, 32, 3), 256, 0, stream>>>(qb, kb, vb, Wqb, Wvb, bq, bv, Qh, Kh, Vt);
  attn_kernel<<<dim3(64, 64), 256, 0, stream>>>(Qh, Kh, Vt, gammas, concat);
  gemm_out<<<dim3(8, 32), 256, 0, stream>>>(concat, Wob, bo, query, xbuf);
  ln_kernel<<<4096, 256, 0, stream>>>(xbuf, ln_g, ln_b, out);
}

// Round 5
// 190.711 us; speedup vs baseline: 4.3803x; 1.0617x over previous
//
#include <hip/hip_runtime.h>
#include <hip/hip_bf16.h>
#include <stdint.h>

// ---------------------------------------------------------------------------
// DTransformer layer on MI355X.  B=4, T=1024, D=1024, H=16, dk=64.
//   1. conv f32 -> bf16 (single batched launch)
//   2. gemm_proj: Q,K (B,H,T,64), V -> transposed (B,H,64,T)
//   3. attn (512 thr, 8 waves): QK^T (MFMA, bf16 S in LDS) -> causally-tiered
//      no-max-subtraction softmax in exp2 domain (2 cross-lane stages/row,
//      2 rows/wave) -> gamma effect -> softmax+maxout -> P bf16 -> PV MFMA
//   4. gemm_out: x = concat@Wo^T + bo + query   5. layernorm
// ---------------------------------------------------------------------------

typedef unsigned short ushort_t;
typedef __attribute__((ext_vector_type(8))) short short8;
typedef __attribute__((ext_vector_type(8))) unsigned short u16x8;
typedef __attribute__((ext_vector_type(4))) float f32x4;
typedef __attribute__((ext_vector_type(4))) unsigned short u16x4;

#define GLB_CAST(p) ((const __attribute__((address_space(1))) void*)(p))
#define LDS_CAST(p) ((__attribute__((address_space(3))) void*)(p))

#if __has_builtin(__builtin_amdgcn_exp2f)
#define EXP2F(x) __builtin_amdgcn_exp2f(x)
#else
#define EXP2F(x) exp2f(x)
#endif

#define LOG2E 1.44269504f

__device__ __forceinline__ float b2f(ushort_t u) {
  union { unsigned int i; float f; } x; x.i = ((unsigned int)u) << 16; return x.f;
}
__device__ __forceinline__ ushort_t f2b(float f) {   // RNE via hw convert
  __hip_bfloat16 h = __float2bfloat16(f);
  return *reinterpret_cast<ushort_t*>(&h);
}
__device__ __forceinline__ float wave_sum(float v) {
  #pragma unroll
  for (int d = 32; d > 0; d >>= 1) v += __shfl_xor(v, d);
  return v;
}

// ---------------------------------------------------------------------------
// batched f32 -> bf16 converts: y 0..2 tokens (4096 blk), y 3..5 weights (1024)
// ---------------------------------------------------------------------------
__global__ void conv6_f32_bf16(const float* __restrict__ s0, const float* __restrict__ s1,
                               const float* __restrict__ s2, const float* __restrict__ s3,
                               const float* __restrict__ s4, const float* __restrict__ s5,
                               ushort_t* __restrict__ d0, ushort_t* __restrict__ d1,
                               ushort_t* __restrict__ d2, ushort_t* __restrict__ d3,
                               ushort_t* __restrict__ d4, ushort_t* __restrict__ d5,
                               int n4tok, int n4w) {
  const int y = blockIdx.y;
  const float* srcs[6] = {s0, s1, s2, s3, s4, s5};
  ushort_t*    dsts[6] = {d0, d1, d2, d3, d4, d5};
  const int n4 = (y < 3) ? n4tok : n4w;
  int i = blockIdx.x * blockDim.x + threadIdx.x;
  if (i < n4) {
    const float4 v = reinterpret_cast<const float4*>(srcs[y])[i];
    u16x4 o;
    o[0] = f2b(v.x); o[1] = f2b(v.y); o[2] = f2b(v.z); o[3] = f2b(v.w);
    reinterpret_cast<u16x4*>(dsts[y])[i] = o;
  }
}

// ---------------------------------------------------------------------------
// 128x128 tile bf16 GEMM core: C[m,n] = sum_k A[m,k]*Bt[n,k]
// ---------------------------------------------------------------------------
__device__ __forceinline__ void gemm_core(const ushort_t* __restrict__ A,
                                          const ushort_t* __restrict__ Bt,
                                          int m0, int n0,
                                          ushort_t* As, ushort_t* Bs,
                                          f32x4 (&acc)[4][4]) {
  const int tid = threadIdx.x, lane = tid & 63;
  const int wid = tid >> 6;
  const int wr = (wid >> 1) * 64, wc = (wid & 1) * 64;
  for (int k0 = 0; k0 < 1024; k0 += 32) {
    #pragma unroll
    for (int it = 0; it < 2; ++it) {
      const int idx = tid * 8 + it * 2048;
      const int r = idx >> 5, kk = idx & 31;
      __builtin_amdgcn_global_load_lds(GLB_CAST(&A[(size_t)(m0 + r) * 1024 + k0 + kk]),
                                       LDS_CAST(&As[idx]), 16, 0, 0);
      __builtin_amdgcn_global_load_lds(GLB_CAST(&Bt[(size_t)(n0 + r) * 1024 + k0 + kk]),
                                       LDS_CAST(&Bs[idx]), 16, 0, 0);
    }
    __syncthreads();
    short8 af[4], bfv[4];
    #pragma unroll
    for (int m = 0; m < 4; ++m)
      af[m] = *reinterpret_cast<const short8*>(&As[(wr + m * 16 + (lane & 15)) * 32 + (lane >> 4) * 8]);
    #pragma unroll
    for (int n = 0; n < 4; ++n)
      bfv[n] = *reinterpret_cast<const short8*>(&Bs[(wc + n * 16 + (lane & 15)) * 32 + (lane >> 4) * 8]);
    #pragma unroll
    for (int m = 0; m < 4; ++m)
      #pragma unroll
      for (int n = 0; n < 4; ++n)
        acc[m][n] = __builtin_amdgcn_mfma_f32_16x16x32_bf16(af[m], bfv[n], acc[m][n], 0, 0, 0);
    __syncthreads();
  }
}

// QKV projections. z=0: Q, z=1: K -> (B,H,T,64); z=2: V -> TRANSPOSED (B,H,64,T)
__global__ __launch_bounds__(256) void gemm_proj(
    const ushort_t* __restrict__ qb, const ushort_t* __restrict__ kb, const ushort_t* __restrict__ vb,
    const ushort_t* __restrict__ Wqb, const ushort_t* __restrict__ Wvb,
    const float* __restrict__ bq, const float* __restrict__ bvv,
    ushort_t* __restrict__ Qh, ushort_t* __restrict__ Kh, ushort_t* __restrict__ Vt) {
  __shared__ ushort_t As[128 * 32], Bs[128 * 32];
  const ushort_t* A; const ushort_t* Bt; const float* bias;
  if (blockIdx.z == 0)      { A = qb; Bt = Wqb; bias = bq;  }
  else if (blockIdx.z == 1) { A = kb; Bt = Wqb; bias = bq;  }
  else                      { A = vb; Bt = Wvb; bias = bvv; }
  const int m0 = blockIdx.y * 128, n0 = blockIdx.x * 128;
  f32x4 zero = {0.f, 0.f, 0.f, 0.f};
  f32x4 acc[4][4];
  #pragma unroll
  for (int m = 0; m < 4; ++m)
    #pragma unroll
    for (int n = 0; n < 4; ++n) acc[m][n] = zero;
  gemm_core(A, Bt, m0, n0, As, Bs, acc);
  const int lane = threadIdx.x & 63, wid = threadIdx.x >> 6;
  const int wr = (wid >> 1) * 64, wc = (wid & 1) * 64;
  if (blockIdx.z == 2) {
    #pragma unroll
    for (int m = 0; m < 4; ++m)
      #pragma unroll
      for (int n = 0; n < 4; ++n) {
        const int rowb = m0 + wr + m * 16 + (lane >> 4) * 4;
        const int col  = n0 + wc + n * 16 + (lane & 15);
        u16x4 pk;
        #pragma unroll
        for (int r4 = 0; r4 < 4; ++r4) pk[r4] = f2b(acc[m][n][r4] + bias[col]);
        const int bi = rowb >> 10, t = rowb & 1023;
        *reinterpret_cast<u16x4*>(
            &Vt[((size_t)(bi * 16 + (col >> 6)) * 64 + (col & 63)) * 1024 + t]) = pk;
      }
  } else {
    ushort_t* dst = (blockIdx.z == 0) ? Qh : Kh;
    #pragma unroll
    for (int m = 0; m < 4; ++m)
      #pragma unroll
      for (int n = 0; n < 4; ++n)
        #pragma unroll
        for (int r4 = 0; r4 < 4; ++r4) {
          const int row = m0 + wr + m * 16 + (lane >> 4) * 4 + r4;
          const int col = n0 + wc + n * 16 + (lane & 15);
          const float v = acc[m][n][r4] + bias[col];
          const int bi = row >> 10, t = row & 1023, h = col >> 6, dd = col & 63;
          dst[((size_t)(bi * 16 + h) * 1024 + t) * 64 + dd] = f2b(v);
        }
  }
}

// Output projection: x = concat@Wo^T + bo + query   (f32)
__global__ __launch_bounds__(256) void gemm_out(
    const ushort_t* __restrict__ A, const ushort_t* __restrict__ Bt,
    const float* __restrict__ bias, const float* __restrict__ resid,
    float* __restrict__ dstF) {
  __shared__ ushort_t As[128 * 32], Bs[128 * 32];
  const int m0 = blockIdx.y * 128, n0 = blockIdx.x * 128;
  f32x4 zero = {0.f, 0.f, 0.f, 0.f};
  f32x4 acc[4][4];
  #pragma unroll
  for (int m = 0; m < 4; ++m)
    #pragma unroll
    for (int n = 0; n < 4; ++n) acc[m][n] = zero;
  gemm_core(A, Bt, m0, n0, As, Bs, acc);
  const int lane = threadIdx.x & 63, wid = threadIdx.x >> 6;
  const int wr = (wid >> 1) * 64, wc = (wid & 1) * 64;
  #pragma unroll
  for (int m = 0; m < 4; ++m)
    #pragma unroll
    for (int n = 0; n < 4; ++n)
      #pragma unroll
      for (int r4 = 0; r4 < 4; ++r4) {
        const int row = m0 + wr + m * 16 + (lane >> 4) * 4 + r4;
        const int col = n0 + wc + n * 16 + (lane & 15);
        const size_t o = (size_t)row * 1024 + col;
        dstF[o] = acc[m][n][r4] + bias[col] + resid[o];
      }
}

// ---------------------------------------------------------------------------
// Phase B worker, CH columns per lane (lane L owns cols [CH*L, CH*(L+1))).
// 8 waves, 2 rows per wave.  No max-subtraction (scores are O(1); exp2-safe).
// Cross-lane stages per row: 1 suffix-scan + 1 fused sum/max reduce.
// ---------------------------------------------------------------------------
template<int CH>
__device__ __forceinline__ void phase_b(ushort_t* __restrict__ Sb, const int i0,
                                        const int w, const int lane, const float gamx) {
  const int c0 = CH * lane;
  int idxA = 0, idxB = 0;
  if constexpr (CH == 16) {
    const int ca = 2 * lane, cb = 2 * lane + 1;
    idxA = (ca ^ ((ca >> 3) & 7)) << 3;
    idxB = (cb ^ ((cb >> 3) & 7)) << 3;
  } else {
    const int c = c0 >> 3;
    idxA = ((c ^ ((c >> 3) & 7)) << 3) + (c0 & 7);
  }
  #pragma unroll
  for (int rr = 0; rr < 2; ++rr) {
    const int r = w * 2 + rr;
    const int i = i0 + r;
    ushort_t* __restrict__ Row = &Sb[r * 1032];
    if (i == 0) {                       // fully masked row -> P = 0
      #pragma unroll
      for (int e = 0; e < CH; ++e) {
        if constexpr (CH == 16) Row[(e < 8) ? (idxA + e) : (idxB + e - 8)] = 0;
        else                    Row[idxA + e] = 0;
      }
      continue;
    }
    float s[CH];
    if constexpr (CH == 16) {
      const u16x8 ra = *reinterpret_cast<const u16x8*>(&Row[idxA]);
      const u16x8 rb = *reinterpret_cast<const u16x8*>(&Row[idxB]);
      #pragma unroll
      for (int e = 0; e < 8; ++e) { s[e] = b2f(ra[e]); s[8 + e] = b2f(rb[e]); }
    } else if constexpr (CH == 8) {
      const u16x8 ra = *reinterpret_cast<const u16x8*>(&Row[idxA]);
      #pragma unroll
      for (int e = 0; e < 8; ++e) s[e] = b2f(ra[e]);
    } else if constexpr (CH == 4) {
      const u16x4 ra = *reinterpret_cast<const u16x4*>(&Row[idxA]);
      #pragma unroll
      for (int e = 0; e < 4; ++e) s[e] = b2f(ra[e]);
    } else if constexpr (CH == 2) {
      s[0] = b2f(Row[idxA]); s[1] = b2f(Row[idxA + 1]);
    } else {
      s[0] = b2f(Row[idxA]);
    }
    const int nact = min(max(i - c0, 0), CH);
    #pragma unroll
    for (int e = 0; e < CH; ++e)
      s[e] = (e < nact) ? s[e] * LOG2E : -__builtin_inff();
    // exp (no max-sub) + in-lane total
    float ev[CH];
    float run = 0.f;
    #pragma unroll
    for (int e = 0; e < CH; ++e) { ev[e] = EXP2F(s[e]); run += ev[e]; }
    // wave-level inclusive suffix of lane totals -> Z1, excl
    float v = run;
    #pragma unroll
    for (int d = 1; d < 64; d <<= 1) {
      const float t = __shfl_down(v, d);
      v += (lane + d < 64) ? t : 0.f;
    }
    const float Z1 = __shfl(v, 0);
    const float excl = v - run;
    // gamma distance effect (downward pass recomputes tails; no tl[] array)
    const float g2 = -gamx * rsqrtf(Z1);
    const float posb = (float)(i - c0);
    float run2 = excl;
    #pragma unroll
    for (int e = CH - 1; e >= 0; --e) {
      const float t = fmaxf(run2 * (posb - (float)e), 0.f);
      run2 += ev[e];
      const float eff = fmaxf(EXP2F(g2 * sqrtf(t)), 1e-5f);
      s[e] *= eff;                      // -inf stays -inf (eff in (0,1])
    }
    // second exp + fused sum/max reduce (two independent shfl chains)
    float z2 = 0.f, mm = 0.f;
    #pragma unroll
    for (int e = 0; e < CH; ++e) {
      ev[e] = EXP2F(s[e]);
      z2 += ev[e];
      mm = fmaxf(mm, ev[e]);
    }
    #pragma unroll
    for (int d = 32; d > 0; d >>= 1) {
      z2 += __shfl_xor(z2, d);
      mm = fmaxf(mm, __shfl_xor(mm, d));
    }
    const float sc = fminf(1.f / mm, 5.f / z2);   // maxout-combined normalizer
    if constexpr (CH == 16) {
      u16x8 oa, ob;
      #pragma unroll
      for (int e = 0; e < 8; ++e) { oa[e] = f2b(ev[e] * sc); ob[e] = f2b(ev[8 + e] * sc); }
      *reinterpret_cast<u16x8*>(&Row[idxA]) = oa;
      *reinterpret_cast<u16x8*>(&Row[idxB]) = ob;
    } else if constexpr (CH == 8) {
      u16x8 oa;
      #pragma unroll
      for (int e = 0; e < 8; ++e) oa[e] = f2b(ev[e] * sc);
      *reinterpret_cast<u16x8*>(&Row[idxA]) = oa;
    } else if constexpr (CH == 4) {
      u16x4 oa;
      #pragma unroll
      for (int e = 0; e < 4; ++e) oa[e] = f2b(ev[e] * sc);
      *reinterpret_cast<u16x4*>(&Row[idxA]) = oa;
    } else if constexpr (CH == 2) {
      Row[idxA] = f2b(ev[0] * sc); Row[idxA + 1] = f2b(ev[1] * sc);
    } else {
      Row[idxA] = f2b(ev[0] * sc);
    }
  }
}

// ---------------------------------------------------------------------------
// Attention.  grid = (T/16, B*H), 512 threads (8 waves).
// ---------------------------------------------------------------------------
__global__ __launch_bounds__(512, 6) void attn_kernel(
    const ushort_t* __restrict__ Qh, const ushort_t* __restrict__ Kh,
    const ushort_t* __restrict__ Vt, const float* __restrict__ gammas,
    ushort_t* __restrict__ concat) {
  __shared__ __align__(16) ushort_t Sb[16 * 1032];
  __shared__ __align__(16) ushort_t Qs[16 * 72];     // padded stride 72
  const int tid = threadIdx.x, lane = tid & 63, w = tid >> 6;
  const int bh = blockIdx.y, bi = bh >> 4, h = bh & 15;
  const int i0 = blockIdx.x * 16;
  const size_t base = (size_t)bh * (1024 * 64);

  if (tid < 256) { // stage Q tile (16 rows x 64)
    const int r = tid >> 4, d = (tid & 15) * 4;
    *reinterpret_cast<u16x4*>(&Qs[r * 72 + d]) =
        *reinterpret_cast<const u16x4*>(&Qh[base + (size_t)(i0 + r) * 64 + d]);
  }
  __syncthreads();

  // ---- Phase A: scores -> bf16 S (swizzled), 8-wave round robin ----
  const int upper = i0 + 16;
  for (int nt = 0; nt < 8; ++nt) {
    const int colbase = (nt * 8 + w) * 16;
    if (colbase >= upper) break;
    f32x4 acc = {0.f, 0.f, 0.f, 0.f};
    #pragma unroll
    for (int kt = 0; kt < 2; ++kt) {
      const short8 a = *reinterpret_cast<const short8*>(
          &Qs[(lane & 15) * 72 + kt * 32 + (lane >> 4) * 8]);
      const short8 bb = *reinterpret_cast<const short8*>(
          &Kh[base + (size_t)(colbase + (lane & 15)) * 64 + kt * 32 + (lane >> 4) * 8]);
      acc = __builtin_amdgcn_mfma_f32_16x16x32_bf16(a, bb, acc, 0, 0, 0);
    }
    const int j = colbase + (lane & 15);
    const int cq = (j >> 3) ^ ((j >> 6) & 7);
    const int ub = cq * 8 + (j & 7);
    #pragma unroll
    for (int r4 = 0; r4 < 4; ++r4) {
      const int rf = (lane >> 4) * 4 + r4;
      Sb[rf * 1032 + ub] = f2b(acc[r4] * 0.125f);
    }
  }
  __syncthreads();

  // ---- Phase B: causally tiered, 2 rows/wave ----
  const float gamx = fabsf(gammas[h]) * LOG2E;
  const int chp = (upper + 63) >> 6;        // cols/lane needed (block-uniform)
  if (chp == 1)      phase_b<1>(Sb, i0, w, lane, gamx);
  else if (chp == 2) phase_b<2>(Sb, i0, w, lane, gamx);
  else if (chp <= 4) phase_b<4>(Sb, i0, w, lane, gamx);
  else if (chp <= 8) phase_b<8>(Sb, i0, w, lane, gamx);
  else               phase_b<16>(Sb, i0, w, lane, gamx);
  __syncthreads();

  // ---- Phase C: PV via MFMA on waves 0-3.  wave w -> d-tile d0 = w*16 ----
  if (w < 4) {
    const int d0 = w * 16;
    const int arow = lane & 15;
    const ushort_t* Prow = &Sb[arow * 1032];
    const ushort_t* Vrow = Vt + base + (size_t)(d0 + arow) * 1024;
    const int kmax = (upper + 31) & ~31;
    f32x4 acc = {0.f, 0.f, 0.f, 0.f};
    for (int k0 = 0; k0 < kmax; k0 += 32) {
      const int c = (k0 >> 3) + (lane >> 4);
      const int cq = c ^ ((c >> 3) & 7);
      const short8 a = *reinterpret_cast<const short8*>(&Prow[cq * 8]);
      const short8 bb = *reinterpret_cast<const short8*>(&Vrow[k0 + (lane >> 4) * 8]);
      acc = __builtin_amdgcn_mfma_f32_16x16x32_bf16(a, bb, acc, 0, 0, 0);
    }
    #pragma unroll
    for (int r4 = 0; r4 < 4; ++r4) {
      const int row = (lane >> 4) * 4 + r4;
      const int i = i0 + row;
      concat[((size_t)(bi * 1024 + i)) * 1024 + h * 64 + d0 + arow] = f2b(acc[r4]);
    }
  }
}

// ---------------------------------------------------------------------------
__global__ __launch_bounds__(256) void ln_kernel(const float* __restrict__ x,
                                                 const float* __restrict__ g,
                                                 const float* __restrict__ bb,
                                                 float* __restrict__ out) {
  const int row = blockIdx.x, tid = threadIdx.x, lane = tid & 63, w = tid >> 6;
  const float4 v = reinterpret_cast<const float4*>(x + (size_t)row * 1024)[tid];
  float s = v.x + v.y + v.z + v.w;
  float q = v.x * v.x + v.y * v.y + v.z * v.z + v.w * v.w;
  s = wave_sum(s); q = wave_sum(q);
  __shared__ float ps[4], pq[4];
  if (lane == 0) { ps[w] = s; pq[w] = q; }
  __syncthreads();
  const float ts = ps[0] + ps[1] + ps[2] + ps[3];
  const float tq = pq[0] + pq[1] + pq[2] + pq[3];
  const float mu = ts * (1.f / 1024.f);
  const float inv = rsqrtf(tq * (1.f / 1024.f) - mu * mu + 1e-5f);
  const float4 gv = reinterpret_cast<const float4*>(g)[tid];
  const float4 bv = reinterpret_cast<const float4*>(bb)[tid];
  float4 o;
  o.x = (v.x - mu) * inv * gv.x + bv.x;
  o.y = (v.y - mu) * inv * gv.y + bv.y;
  o.z = (v.z - mu) * inv * gv.z + bv.z;
  o.w = (v.w - mu) * inv * gv.w + bv.w;
  reinterpret_cast<float4*>(out + (size_t)row * 1024)[tid] = o;
}

// ---------------------------------------------------------------------------
extern "C" void kernel_launch(void* const* d_in, const int* in_sizes, int n_in,
                              void* d_out, int out_size, void* d_ws, size_t ws_size,
                              hipStream_t stream) {
  (void)in_sizes; (void)n_in; (void)out_size; (void)ws_size;
  const float* query  = (const float*)d_in[0];
  const float* key    = (const float*)d_in[1];
  const float* values = (const float*)d_in[2];
  const float* Wq     = (const float*)d_in[3];
  const float* bq     = (const float*)d_in[4];
  const float* Wv     = (const float*)d_in[5];
  const float* bv     = (const float*)d_in[6];
  const float* Wo     = (const float*)d_in[7];
  const float* bo     = (const float*)d_in[8];
  const float* gammas = (const float*)d_in[9];
  const float* ln_g   = (const float*)d_in[10];
  const float* ln_b   = (const float*)d_in[11];
  float* out = (float*)d_out;

  const size_t NT = 4096ull * 1024;
  const size_t NW = 1024ull * 1024;
  char* p = (char*)d_ws;
  ushort_t* qb  = (ushort_t*)p; p += NT * 2;
  ushort_t* kb  = (ushort_t*)p; p += NT * 2;
  ushort_t* vb  = (ushort_t*)p; p += NT * 2;
  ushort_t* Wqb = (ushort_t*)p; p += NW * 2;
  ushort_t* Wvb = (ushort_t*)p; p += NW * 2;
  ushort_t* Wob = (ushort_t*)p; p += NW * 2;
  ushort_t* Qh  = (ushort_t*)p; p += NT * 2;
  ushort_t* Kh  = (ushort_t*)p; p += NT * 2;
  ushort_t* Vt  = (ushort_t*)p; p += NT * 2;
  ushort_t* concat = vb;                // free after gemm_proj
  float*    xbuf   = (float*)qb;        // spans qb+kb, free after gemm_proj

  conv6_f32_bf16<<<dim3(4096, 6), 256, 0, stream>>>(
      query, key, values, Wq, Wv, Wo, qb, kb, vb, Wqb, Wvb, Wob,
      (int)(NT / 4), (int)(NW / 4));

  gemm_proj<<<dim3(8, 32, 3), 256, 0, stream>>>(qb, kb, vb, Wqb, Wvb, bq, bv, Qh, Kh, Vt);
  attn_kernel<<<dim3(64, 64), 512, 0, stream>>>(Qh, Kh, Vt, gammas, concat);
  gemm_out<<<dim3(8, 32), 256, 0, stream>>>(concat, Wob, bo, query, xbuf);
  ln_kernel<<<4096, 256, 0, stream>>>(xbuf, ln_g, ln_b, out);
}

// Round 6
// 181.008 us; speedup vs baseline: 4.6151x; 1.0536x over previous
//
#include <hip/hip_runtime.h>
#include <hip/hip_bf16.h>
#include <stdint.h>

// ---------------------------------------------------------------------------
// DTransformer layer on MI355X.  B=4, T=1024, D=1024, H=16, dk=64.
//   1. conv f32 -> bf16 (single batched launch)
//   2. gemm_proj: Q,K (B,H,T,64), V -> transposed (B,H,64,T)
//   3. attn (256 thr, 4 waves, XCD-swizzled grid): QK^T (MFMA) -> tiered
//      no-max-sub softmax in exp2 domain, s[]-only live (recompute exp2) ->
//      gamma effect -> softmax+maxout -> P bf16 -> PV via MFMA
//   4. gemm_out: x = concat@Wo^T + bo + query   5. layernorm
// ---------------------------------------------------------------------------

typedef unsigned short ushort_t;
typedef __attribute__((ext_vector_type(8))) short short8;
typedef __attribute__((ext_vector_type(8))) unsigned short u16x8;
typedef __attribute__((ext_vector_type(4))) float f32x4;
typedef __attribute__((ext_vector_type(4))) unsigned short u16x4;

#define GLB_CAST(p) ((const __attribute__((address_space(1))) void*)(p))
#define LDS_CAST(p) ((__attribute__((address_space(3))) void*)(p))

#if __has_builtin(__builtin_amdgcn_exp2f)
#define EXP2F(x) __builtin_amdgcn_exp2f(x)
#else
#define EXP2F(x) exp2f(x)
#endif

#define LOG2E 1.44269504f

__device__ __forceinline__ float b2f(ushort_t u) {
  union { unsigned int i; float f; } x; x.i = ((unsigned int)u) << 16; return x.f;
}
__device__ __forceinline__ ushort_t f2b(float f) {   // RNE via hw convert
  __hip_bfloat16 h = __float2bfloat16(f);
  return *reinterpret_cast<ushort_t*>(&h);
}
__device__ __forceinline__ float wave_sum(float v) {
  #pragma unroll
  for (int d = 32; d > 0; d >>= 1) v += __shfl_xor(v, d);
  return v;
}

// ---------------------------------------------------------------------------
// batched f32 -> bf16 converts: y 0..2 tokens (4096 blk), y 3..5 weights (1024)
// ---------------------------------------------------------------------------
__global__ void conv6_f32_bf16(const float* __restrict__ s0, const float* __restrict__ s1,
                               const float* __restrict__ s2, const float* __restrict__ s3,
                               const float* __restrict__ s4, const float* __restrict__ s5,
                               ushort_t* __restrict__ d0, ushort_t* __restrict__ d1,
                               ushort_t* __restrict__ d2, ushort_t* __restrict__ d3,
                               ushort_t* __restrict__ d4, ushort_t* __restrict__ d5,
                               int n4tok, int n4w) {
  const int y = blockIdx.y;
  const float* srcs[6] = {s0, s1, s2, s3, s4, s5};
  ushort_t*    dsts[6] = {d0, d1, d2, d3, d4, d5};
  const int n4 = (y < 3) ? n4tok : n4w;
  int i = blockIdx.x * blockDim.x + threadIdx.x;
  if (i < n4) {
    const float4 v = reinterpret_cast<const float4*>(srcs[y])[i];
    u16x4 o;
    o[0] = f2b(v.x); o[1] = f2b(v.y); o[2] = f2b(v.z); o[3] = f2b(v.w);
    reinterpret_cast<u16x4*>(dsts[y])[i] = o;
  }
}

// ---------------------------------------------------------------------------
// 128x128 tile bf16 GEMM core: C[m,n] = sum_k A[m,k]*Bt[n,k]
// ---------------------------------------------------------------------------
__device__ __forceinline__ void gemm_core(const ushort_t* __restrict__ A,
                                          const ushort_t* __restrict__ Bt,
                                          int m0, int n0,
                                          ushort_t* As, ushort_t* Bs,
                                          f32x4 (&acc)[4][4]) {
  const int tid = threadIdx.x, lane = tid & 63;
  const int wid = tid >> 6;
  const int wr = (wid >> 1) * 64, wc = (wid & 1) * 64;
  for (int k0 = 0; k0 < 1024; k0 += 32) {
    #pragma unroll
    for (int it = 0; it < 2; ++it) {
      const int idx = tid * 8 + it * 2048;
      const int r = idx >> 5, kk = idx & 31;
      __builtin_amdgcn_global_load_lds(GLB_CAST(&A[(size_t)(m0 + r) * 1024 + k0 + kk]),
                                       LDS_CAST(&As[idx]), 16, 0, 0);
      __builtin_amdgcn_global_load_lds(GLB_CAST(&Bt[(size_t)(n0 + r) * 1024 + k0 + kk]),
                                       LDS_CAST(&Bs[idx]), 16, 0, 0);
    }
    __syncthreads();
    short8 af[4], bfv[4];
    #pragma unroll
    for (int m = 0; m < 4; ++m)
      af[m] = *reinterpret_cast<const short8*>(&As[(wr + m * 16 + (lane & 15)) * 32 + (lane >> 4) * 8]);
    #pragma unroll
    for (int n = 0; n < 4; ++n)
      bfv[n] = *reinterpret_cast<const short8*>(&Bs[(wc + n * 16 + (lane & 15)) * 32 + (lane >> 4) * 8]);
    #pragma unroll
    for (int m = 0; m < 4; ++m)
      #pragma unroll
      for (int n = 0; n < 4; ++n)
        acc[m][n] = __builtin_amdgcn_mfma_f32_16x16x32_bf16(af[m], bfv[n], acc[m][n], 0, 0, 0);
    __syncthreads();
  }
}

// QKV projections. z=0: Q, z=1: K -> (B,H,T,64); z=2: V -> TRANSPOSED (B,H,64,T)
__global__ __launch_bounds__(256) void gemm_proj(
    const ushort_t* __restrict__ qb, const ushort_t* __restrict__ kb, const ushort_t* __restrict__ vb,
    const ushort_t* __restrict__ Wqb, const ushort_t* __restrict__ Wvb,
    const float* __restrict__ bq, const float* __restrict__ bvv,
    ushort_t* __restrict__ Qh, ushort_t* __restrict__ Kh, ushort_t* __restrict__ Vt) {
  __shared__ ushort_t As[128 * 32], Bs[128 * 32];
  const ushort_t* A; const ushort_t* Bt; const float* bias;
  if (blockIdx.z == 0)      { A = qb; Bt = Wqb; bias = bq;  }
  else if (blockIdx.z == 1) { A = kb; Bt = Wqb; bias = bq;  }
  else                      { A = vb; Bt = Wvb; bias = bvv; }
  const int m0 = blockIdx.y * 128, n0 = blockIdx.x * 128;
  f32x4 zero = {0.f, 0.f, 0.f, 0.f};
  f32x4 acc[4][4];
  #pragma unroll
  for (int m = 0; m < 4; ++m)
    #pragma unroll
    for (int n = 0; n < 4; ++n) acc[m][n] = zero;
  gemm_core(A, Bt, m0, n0, As, Bs, acc);
  const int lane = threadIdx.x & 63, wid = threadIdx.x >> 6;
  const int wr = (wid >> 1) * 64, wc = (wid & 1) * 64;
  if (blockIdx.z == 2) {
    #pragma unroll
    for (int m = 0; m < 4; ++m)
      #pragma unroll
      for (int n = 0; n < 4; ++n) {
        const int rowb = m0 + wr + m * 16 + (lane >> 4) * 4;
        const int col  = n0 + wc + n * 16 + (lane & 15);
        u16x4 pk;
        #pragma unroll
        for (int r4 = 0; r4 < 4; ++r4) pk[r4] = f2b(acc[m][n][r4] + bias[col]);
        const int bi = rowb >> 10, t = rowb & 1023;
        *reinterpret_cast<u16x4*>(
            &Vt[((size_t)(bi * 16 + (col >> 6)) * 64 + (col & 63)) * 1024 + t]) = pk;
      }
  } else {
    ushort_t* dst = (blockIdx.z == 0) ? Qh : Kh;
    #pragma unroll
    for (int m = 0; m < 4; ++m)
      #pragma unroll
      for (int n = 0; n < 4; ++n)
        #pragma unroll
        for (int r4 = 0; r4 < 4; ++r4) {
          const int row = m0 + wr + m * 16 + (lane >> 4) * 4 + r4;
          const int col = n0 + wc + n * 16 + (lane & 15);
          const float v = acc[m][n][r4] + bias[col];
          const int bi = row >> 10, t = row & 1023, h = col >> 6, dd = col & 63;
          dst[((size_t)(bi * 16 + h) * 1024 + t) * 64 + dd] = f2b(v);
        }
  }
}

// Output projection: x = concat@Wo^T + bo + query   (f32)
__global__ __launch_bounds__(256) void gemm_out(
    const ushort_t* __restrict__ A, const ushort_t* __restrict__ Bt,
    const float* __restrict__ bias, const float* __restrict__ resid,
    float* __restrict__ dstF) {
  __shared__ ushort_t As[128 * 32], Bs[128 * 32];
  const int m0 = blockIdx.y * 128, n0 = blockIdx.x * 128;
  f32x4 zero = {0.f, 0.f, 0.f, 0.f};
  f32x4 acc[4][4];
  #pragma unroll
  for (int m = 0; m < 4; ++m)
    #pragma unroll
    for (int n = 0; n < 4; ++n) acc[m][n] = zero;
  gemm_core(A, Bt, m0, n0, As, Bs, acc);
  const int lane = threadIdx.x & 63, wid = threadIdx.x >> 6;
  const int wr = (wid >> 1) * 64, wc = (wid & 1) * 64;
  #pragma unroll
  for (int m = 0; m < 4; ++m)
    #pragma unroll
    for (int n = 0; n < 4; ++n)
      #pragma unroll
      for (int r4 = 0; r4 < 4; ++r4) {
        const int row = m0 + wr + m * 16 + (lane >> 4) * 4 + r4;
        const int col = n0 + wc + n * 16 + (lane & 15);
        const size_t o = (size_t)row * 1024 + col;
        dstF[o] = acc[m][n][r4] + bias[col] + resid[o];
      }
}

// ---------------------------------------------------------------------------
// Phase B worker, CH columns per lane (lane L owns cols [CH*L, CH*(L+1))).
// 4 waves, 4 rows per wave.  Only s[CH] stays live (exp2 recomputed per pass).
// ---------------------------------------------------------------------------
template<int CH>
__device__ __forceinline__ void phase_b(ushort_t* __restrict__ Sb, const int i0,
                                        const int w, const int lane, const float gamx) {
  const int c0 = CH * lane;
  int idxA = 0, idxB = 0;
  if constexpr (CH == 16) {
    const int ca = 2 * lane, cb = 2 * lane + 1;
    idxA = (ca ^ ((ca >> 3) & 7)) << 3;
    idxB = (cb ^ ((cb >> 3) & 7)) << 3;
  } else {
    const int c = c0 >> 3;
    idxA = ((c ^ ((c >> 3) & 7)) << 3) + (c0 & 7);
  }
  for (int rr = 0; rr < 4; ++rr) {
    const int r = w * 4 + rr;
    const int i = i0 + r;
    ushort_t* __restrict__ Row = &Sb[r * 1032];
    if (i == 0) {                       // fully masked row -> P = 0
      #pragma unroll
      for (int e = 0; e < CH; ++e) {
        if constexpr (CH == 16) Row[(e < 8) ? (idxA + e) : (idxB + e - 8)] = 0;
        else                    Row[idxA + e] = 0;
      }
      continue;
    }
    float s[CH];
    if constexpr (CH == 16) {
      const u16x8 ra = *reinterpret_cast<const u16x8*>(&Row[idxA]);
      const u16x8 rb = *reinterpret_cast<const u16x8*>(&Row[idxB]);
      #pragma unroll
      for (int e = 0; e < 8; ++e) { s[e] = b2f(ra[e]); s[8 + e] = b2f(rb[e]); }
    } else if constexpr (CH == 8) {
      const u16x8 ra = *reinterpret_cast<const u16x8*>(&Row[idxA]);
      #pragma unroll
      for (int e = 0; e < 8; ++e) s[e] = b2f(ra[e]);
    } else if constexpr (CH == 4) {
      const u16x4 ra = *reinterpret_cast<const u16x4*>(&Row[idxA]);
      #pragma unroll
      for (int e = 0; e < 4; ++e) s[e] = b2f(ra[e]);
    } else if constexpr (CH == 2) {
      s[0] = b2f(Row[idxA]); s[1] = b2f(Row[idxA + 1]);
    } else {
      s[0] = b2f(Row[idxA]);
    }
    const int nact = min(max(i - c0, 0), CH);
    // mask + first exp (no max-sub; scores are O(1)) + in-lane total
    float run = 0.f;
    #pragma unroll
    for (int e = 0; e < CH; ++e) {
      s[e] = (e < nact) ? s[e] * LOG2E : -__builtin_inff();
      run += EXP2F(s[e]);
    }
    // wave-level inclusive suffix of lane totals -> Z1, excl
    float v = run;
    #pragma unroll
    for (int d = 1; d < 64; d <<= 1) {
      const float t = __shfl_down(v, d);
      v += (lane + d < 64) ? t : 0.f;
    }
    const float Z1 = __shfl(v, 0);
    const float excl = v - run;
    // gamma distance effect (downward pass; exp2 recomputed, no ev[] array)
    const float g2 = -gamx * rsqrtf(Z1);
    const float posb = (float)(i - c0);
    float run2 = excl;
    #pragma unroll
    for (int e = CH - 1; e >= 0; --e) {
      const float t = fmaxf(run2 * (posb - (float)e), 0.f);
      run2 += EXP2F(s[e]);
      const float eff = fmaxf(EXP2F(g2 * sqrtf(t)), 1e-5f);
      s[e] *= eff;                      // -inf stays -inf (eff in (0,1])
    }
    // second exp: fused sum/max reduce (recomputed p)
    float z2 = 0.f, mm = 0.f;
    #pragma unroll
    for (int e = 0; e < CH; ++e) {
      const float p = EXP2F(s[e]);
      z2 += p;
      mm = fmaxf(mm, p);
    }
    #pragma unroll
    for (int d = 32; d > 0; d >>= 1) {
      z2 += __shfl_xor(z2, d);
      mm = fmaxf(mm, __shfl_xor(mm, d));
    }
    const float sc = fminf(1.f / mm, 5.f / z2);   // maxout-combined normalizer
    if constexpr (CH == 16) {
      u16x8 oa, ob;
      #pragma unroll
      for (int e = 0; e < 8; ++e) {
        oa[e] = f2b(EXP2F(s[e]) * sc);
        ob[e] = f2b(EXP2F(s[8 + e]) * sc);
      }
      *reinterpret_cast<u16x8*>(&Row[idxA]) = oa;
      *reinterpret_cast<u16x8*>(&Row[idxB]) = ob;
    } else if constexpr (CH == 8) {
      u16x8 oa;
      #pragma unroll
      for (int e = 0; e < 8; ++e) oa[e] = f2b(EXP2F(s[e]) * sc);
      *reinterpret_cast<u16x8*>(&Row[idxA]) = oa;
    } else if constexpr (CH == 4) {
      u16x4 oa;
      #pragma unroll
      for (int e = 0; e < 4; ++e) oa[e] = f2b(EXP2F(s[e]) * sc);
      *reinterpret_cast<u16x4*>(&Row[idxA]) = oa;
    } else if constexpr (CH == 2) {
      Row[idxA] = f2b(EXP2F(s[0]) * sc); Row[idxA + 1] = f2b(EXP2F(s[1]) * sc);
    } else {
      Row[idxA] = f2b(EXP2F(s[0]) * sc);
    }
  }
}

// ---------------------------------------------------------------------------
// Attention.  grid = (64, 64) remapped: all 64 i-tiles of one bh on one XCD.
// 256 threads (4 waves).
// ---------------------------------------------------------------------------
__global__ __launch_bounds__(256, 4) void attn_kernel(
    const ushort_t* __restrict__ Qh, const ushort_t* __restrict__ Kh,
    const ushort_t* __restrict__ Vt, const float* __restrict__ gammas,
    ushort_t* __restrict__ concat) {
  __shared__ __align__(16) ushort_t Sb[16 * 1032];
  __shared__ __align__(16) ushort_t Qs[16 * 72];     // padded stride 72
  const int tid = threadIdx.x, lane = tid & 63, w = tid >> 6;
  // XCD swizzle: flat%8 picks XCD (round-robin dispatch); keep one bh per XCD.
  const int flat = blockIdx.x + (blockIdx.y << 6);
  const int bh = ((flat & 7) << 3) | (flat >> 9);
  const int i0 = ((flat >> 3) & 63) << 4;
  const int bi = bh >> 4, h = bh & 15;
  const size_t base = (size_t)bh * (1024 * 64);

  { // stage Q tile (16 rows x 64)
    const int r = tid >> 4, d = (tid & 15) * 4;
    *reinterpret_cast<u16x4*>(&Qs[r * 72 + d]) =
        *reinterpret_cast<const u16x4*>(&Qh[base + (size_t)(i0 + r) * 64 + d]);
  }
  __syncthreads();

  // ---- Phase A: scores -> bf16 S (swizzled) ----
  const int upper = i0 + 16;
  for (int nt = 0; nt < 16; ++nt) {
    const int colbase = (nt * 4 + w) * 16;
    if (colbase >= upper) break;
    f32x4 acc = {0.f, 0.f, 0.f, 0.f};
    #pragma unroll
    for (int kt = 0; kt < 2; ++kt) {
      const short8 a = *reinterpret_cast<const short8*>(
          &Qs[(lane & 15) * 72 + kt * 32 + (lane >> 4) * 8]);
      const short8 bb = *reinterpret_cast<const short8*>(
          &Kh[base + (size_t)(colbase + (lane & 15)) * 64 + kt * 32 + (lane >> 4) * 8]);
      acc = __builtin_amdgcn_mfma_f32_16x16x32_bf16(a, bb, acc, 0, 0, 0);
    }
    const int j = colbase + (lane & 15);
    const int cq = (j >> 3) ^ ((j >> 6) & 7);
    const int ub = cq * 8 + (j & 7);
    #pragma unroll
    for (int r4 = 0; r4 < 4; ++r4) {
      const int rf = (lane >> 4) * 4 + r4;
      Sb[rf * 1032 + ub] = f2b(acc[r4] * 0.125f);
    }
  }
  __syncthreads();

  // ---- Phase B: causally tiered, 4 rows/wave ----
  const float gamx = fabsf(gammas[h]) * LOG2E;
  const int chp = (upper + 63) >> 6;        // cols/lane needed (block-uniform)
  if (chp == 1)      phase_b<1>(Sb, i0, w, lane, gamx);
  else if (chp == 2) phase_b<2>(Sb, i0, w, lane, gamx);
  else if (chp <= 4) phase_b<4>(Sb, i0, w, lane, gamx);
  else if (chp <= 8) phase_b<8>(Sb, i0, w, lane, gamx);
  else               phase_b<16>(Sb, i0, w, lane, gamx);
  __syncthreads();

  // ---- Phase C: PV via MFMA.  wave w -> d-tile d0 = w*16 ----
  {
    const int d0 = w * 16;
    const int arow = lane & 15;
    const ushort_t* Prow = &Sb[arow * 1032];
    const ushort_t* Vrow = Vt + base + (size_t)(d0 + arow) * 1024;
    const int kmax = (upper + 31) & ~31;
    f32x4 acc = {0.f, 0.f, 0.f, 0.f};
    for (int k0 = 0; k0 < kmax; k0 += 32) {
      const int c = (k0 >> 3) + (lane >> 4);
      const int cq = c ^ ((c >> 3) & 7);
      const short8 a = *reinterpret_cast<const short8*>(&Prow[cq * 8]);
      const short8 bb = *reinterpret_cast<const short8*>(&Vrow[k0 + (lane >> 4) * 8]);
      acc = __builtin_amdgcn_mfma_f32_16x16x32_bf16(a, bb, acc, 0, 0, 0);
    }
    #pragma unroll
    for (int r4 = 0; r4 < 4; ++r4) {
      const int row = (lane >> 4) * 4 + r4;
      const int i = i0 + row;
      concat[((size_t)(bi * 1024 + i)) * 1024 + h * 64 + d0 + arow] = f2b(acc[r4]);
    }
  }
}

// ---------------------------------------------------------------------------
__global__ __launch_bounds__(256) void ln_kernel(const float* __restrict__ x,
                                                 const float* __restrict__ g,
                                                 const float* __restrict__ bb,
                                                 float* __restrict__ out) {
  const int row = blockIdx.x, tid = threadIdx.x, lane = tid & 63, w = tid >> 6;
  const float4 v = reinterpret_cast<const float4*>(x + (size_t)row * 1024)[tid];
  float s = v.x + v.y + v.z + v.w;
  float q = v.x * v.x + v.y * v.y + v.z * v.z + v.w * v.w;
  s = wave_sum(s); q = wave_sum(q);
  __shared__ float ps[4], pq[4];
  if (lane == 0) { ps[w] = s; pq[w] = q; }
  __syncthreads();
  const float ts = ps[0] + ps[1] + ps[2] + ps[3];
  const float tq = pq[0] + pq[1] + pq[2] + pq[3];
  const float mu = ts * (1.f / 1024.f);
  const float inv = rsqrtf(tq * (1.f / 1024.f) - mu * mu + 1e-5f);
  const float4 gv = reinterpret_cast<const float4*>(g)[tid];
  const float4 bv = reinterpret_cast<const float4*>(bb)[tid];
  float4 o;
  o.x = (v.x - mu) * inv * gv.x + bv.x;
  o.y = (v.y - mu) * inv * gv.y + bv.y;
  o.z = (v.z - mu) * inv * gv.z + bv.z;
  o.w = (v.w - mu) * inv * gv.w + bv.w;
  reinterpret_cast<float4*>(out + (size_t)row * 1024)[tid] = o;
}

// ---------------------------------------------------------------------------
extern "C" void kernel_launch(void* const* d_in, const int* in_sizes, int n_in,
                              void* d_out, int out_size, void* d_ws, size_t ws_size,
                              hipStream_t stream) {
  (void)in_sizes; (void)n_in; (void)out_size; (void)ws_size;
  const float* query  = (const float*)d_in[0];
  const float* key    = (const float*)d_in[1];
  const float* values = (const float*)d_in[2];
  const float* Wq     = (const float*)d_in[3];
  const float* bq     = (const float*)d_in[4];
  const float* Wv     = (const float*)d_in[5];
  const float* bv     = (const float*)d_in[6];
  const float* Wo     = (const float*)d_in[7];
  const float* bo     = (const float*)d_in[8];
  const float* gammas = (const float*)d_in[9];
  const float* ln_g   = (const float*)d_in[10];
  const float* ln_b   = (const float*)d_in[11];
  float* out = (float*)d_out;

  const size_t NT = 4096ull * 1024;
  const size_t NW = 1024ull * 1024;
  char* p = (char*)d_ws;
  ushort_t* qb  = (ushort_t*)p; p += NT * 2;
  ushort_t* kb  = (ushort_t*)p; p += NT * 2;
  ushort_t* vb  = (ushort_t*)p; p += NT * 2;
  ushort_t* Wqb = (ushort_t*)p; p += NW * 2;
  ushort_t* Wvb = (ushort_t*)p; p += NW * 2;
  ushort_t* Wob = (ushort_t*)p; p += NW * 2;
  ushort_t* Qh  = (ushort_t*)p; p += NT * 2;
  ushort_t* Kh  = (ushort_t*)p; p += NT * 2;
  ushort_t* Vt  = (ushort_t*)p; p += NT * 2;
  ushort_t* concat = vb;                // free after gemm_proj
  float*    xbuf   = (float*)qb;        // spans qb+kb, free after gemm_proj

  conv6_f32_bf16<<<dim3(4096, 6), 256, 0, stream>>>(
      query, key, values, Wq, Wv, Wo, qb, kb, vb, Wqb, Wvb, Wob,
      (int)(NT / 4), (int)(NW / 4));

  gemm_proj<<<dim3(8, 32, 3), 256, 0, stream>>>(qb, kb, vb, Wqb, Wvb, bq, bv, Qh, Kh, Vt);
  attn_kernel<<<dim3(64, 64), 256, 0, stream>>>(Qh, Kh, Vt, gammas, concat);
  gemm_out<<<dim3(8, 32), 256, 0, stream>>>(concat, Wob, bo, query, xbuf);
  ln_kernel<<<4096, 256, 0, stream>>>(xbuf, ln_g, ln_b, out);
}

// Round 7
// 173.546 us; speedup vs baseline: 4.8136x; 1.0430x over previous
//
#include <hip/hip_runtime.h>
#include <hip/hip_bf16.h>
#include <stdint.h>

// ---------------------------------------------------------------------------
// DTransformer layer on MI355X.  B=4, T=1024, D=1024, H=16, dk=64.
//   1. conv f32 -> bf16 (single batched launch)
//   2. gemm_proj: Q,K (B,H,T,64), V -> transposed (B,H,64,T)
//   3. attn (256 thr, 4 waves, XCD-swizzled heaviest-first grid):
//      QK^T (MFMA) -> exact-even-tiered softmax (no max-sub, exp2 domain,
//      s[]+ev[] live, 3 exp2/elem) -> gamma effect -> softmax+maxout ->
//      P bf16 in plain [16][1032] LDS -> PV via MFMA
//   4. gemm_out: x = concat@Wo^T + bo + query   5. layernorm
// ---------------------------------------------------------------------------

typedef unsigned short ushort_t;
typedef __attribute__((ext_vector_type(8))) short short8;
typedef __attribute__((ext_vector_type(8))) unsigned short u16x8;
typedef __attribute__((ext_vector_type(4))) float f32x4;
typedef __attribute__((ext_vector_type(4))) unsigned short u16x4;
typedef __attribute__((ext_vector_type(2))) unsigned short u16x2;

#define GLB_CAST(p) ((const __attribute__((address_space(1))) void*)(p))
#define LDS_CAST(p) ((__attribute__((address_space(3))) void*)(p))

#if __has_builtin(__builtin_amdgcn_exp2f)
#define EXP2F(x) __builtin_amdgcn_exp2f(x)
#else
#define EXP2F(x) exp2f(x)
#endif

#define LOG2E 1.44269504f

__device__ __forceinline__ float b2f(ushort_t u) {
  union { unsigned int i; float f; } x; x.i = ((unsigned int)u) << 16; return x.f;
}
__device__ __forceinline__ ushort_t f2b(float f) {   // RNE via hw convert
  __hip_bfloat16 h = __float2bfloat16(f);
  return *reinterpret_cast<ushort_t*>(&h);
}
__device__ __forceinline__ float wave_sum(float v) {
  #pragma unroll
  for (int d = 32; d > 0; d >>= 1) v += __shfl_xor(v, d);
  return v;
}

// ---------------------------------------------------------------------------
// batched f32 -> bf16 converts: y 0..2 tokens (4096 blk), y 3..5 weights (1024)
// ---------------------------------------------------------------------------
__global__ void conv6_f32_bf16(const float* __restrict__ s0, const float* __restrict__ s1,
                               const float* __restrict__ s2, const float* __restrict__ s3,
                               const float* __restrict__ s4, const float* __restrict__ s5,
                               ushort_t* __restrict__ d0, ushort_t* __restrict__ d1,
                               ushort_t* __restrict__ d2, ushort_t* __restrict__ d3,
                               ushort_t* __restrict__ d4, ushort_t* __restrict__ d5,
                               int n4tok, int n4w) {
  const int y = blockIdx.y;
  const float* srcs[6] = {s0, s1, s2, s3, s4, s5};
  ushort_t*    dsts[6] = {d0, d1, d2, d3, d4, d5};
  const int n4 = (y < 3) ? n4tok : n4w;
  int i = blockIdx.x * blockDim.x + threadIdx.x;
  if (i < n4) {
    const float4 v = reinterpret_cast<const float4*>(srcs[y])[i];
    u16x4 o;
    o[0] = f2b(v.x); o[1] = f2b(v.y); o[2] = f2b(v.z); o[3] = f2b(v.w);
    reinterpret_cast<u16x4*>(dsts[y])[i] = o;
  }
}

// ---------------------------------------------------------------------------
// 128x128 tile bf16 GEMM core: C[m,n] = sum_k A[m,k]*Bt[n,k]
// ---------------------------------------------------------------------------
__device__ __forceinline__ void gemm_core(const ushort_t* __restrict__ A,
                                          const ushort_t* __restrict__ Bt,
                                          int m0, int n0,
                                          ushort_t* As, ushort_t* Bs,
                                          f32x4 (&acc)[4][4]) {
  const int tid = threadIdx.x, lane = tid & 63;
  const int wid = tid >> 6;
  const int wr = (wid >> 1) * 64, wc = (wid & 1) * 64;
  for (int k0 = 0; k0 < 1024; k0 += 32) {
    #pragma unroll
    for (int it = 0; it < 2; ++it) {
      const int idx = tid * 8 + it * 2048;
      const int r = idx >> 5, kk = idx & 31;
      __builtin_amdgcn_global_load_lds(GLB_CAST(&A[(size_t)(m0 + r) * 1024 + k0 + kk]),
                                       LDS_CAST(&As[idx]), 16, 0, 0);
      __builtin_amdgcn_global_load_lds(GLB_CAST(&Bt[(size_t)(n0 + r) * 1024 + k0 + kk]),
                                       LDS_CAST(&Bs[idx]), 16, 0, 0);
    }
    __syncthreads();
    short8 af[4], bfv[4];
    #pragma unroll
    for (int m = 0; m < 4; ++m)
      af[m] = *reinterpret_cast<const short8*>(&As[(wr + m * 16 + (lane & 15)) * 32 + (lane >> 4) * 8]);
    #pragma unroll
    for (int n = 0; n < 4; ++n)
      bfv[n] = *reinterpret_cast<const short8*>(&Bs[(wc + n * 16 + (lane & 15)) * 32 + (lane >> 4) * 8]);
    #pragma unroll
    for (int m = 0; m < 4; ++m)
      #pragma unroll
      for (int n = 0; n < 4; ++n)
        acc[m][n] = __builtin_amdgcn_mfma_f32_16x16x32_bf16(af[m], bfv[n], acc[m][n], 0, 0, 0);
    __syncthreads();
  }
}

// QKV projections. z=0: Q, z=1: K -> (B,H,T,64); z=2: V -> TRANSPOSED (B,H,64,T)
__global__ __launch_bounds__(256) void gemm_proj(
    const ushort_t* __restrict__ qb, const ushort_t* __restrict__ kb, const ushort_t* __restrict__ vb,
    const ushort_t* __restrict__ Wqb, const ushort_t* __restrict__ Wvb,
    const float* __restrict__ bq, const float* __restrict__ bvv,
    ushort_t* __restrict__ Qh, ushort_t* __restrict__ Kh, ushort_t* __restrict__ Vt) {
  __shared__ ushort_t As[128 * 32], Bs[128 * 32];
  const ushort_t* A; const ushort_t* Bt; const float* bias;
  if (blockIdx.z == 0)      { A = qb; Bt = Wqb; bias = bq;  }
  else if (blockIdx.z == 1) { A = kb; Bt = Wqb; bias = bq;  }
  else                      { A = vb; Bt = Wvb; bias = bvv; }
  const int m0 = blockIdx.y * 128, n0 = blockIdx.x * 128;
  f32x4 zero = {0.f, 0.f, 0.f, 0.f};
  f32x4 acc[4][4];
  #pragma unroll
  for (int m = 0; m < 4; ++m)
    #pragma unroll
    for (int n = 0; n < 4; ++n) acc[m][n] = zero;
  gemm_core(A, Bt, m0, n0, As, Bs, acc);
  const int lane = threadIdx.x & 63, wid = threadIdx.x >> 6;
  const int wr = (wid >> 1) * 64, wc = (wid & 1) * 64;
  if (blockIdx.z == 2) {
    #pragma unroll
    for (int m = 0; m < 4; ++m)
      #pragma unroll
      for (int n = 0; n < 4; ++n) {
        const int rowb = m0 + wr + m * 16 + (lane >> 4) * 4;
        const int col  = n0 + wc + n * 16 + (lane & 15);
        u16x4 pk;
        #pragma unroll
        for (int r4 = 0; r4 < 4; ++r4) pk[r4] = f2b(acc[m][n][r4] + bias[col]);
        const int bi = rowb >> 10, t = rowb & 1023;
        *reinterpret_cast<u16x4*>(
            &Vt[((size_t)(bi * 16 + (col >> 6)) * 64 + (col & 63)) * 1024 + t]) = pk;
      }
  } else {
    ushort_t* dst = (blockIdx.z == 0) ? Qh : Kh;
    #pragma unroll
    for (int m = 0; m < 4; ++m)
      #pragma unroll
      for (int n = 0; n < 4; ++n)
        #pragma unroll
        for (int r4 = 0; r4 < 4; ++r4) {
          const int row = m0 + wr + m * 16 + (lane >> 4) * 4 + r4;
          const int col = n0 + wc + n * 16 + (lane & 15);
          const float v = acc[m][n][r4] + bias[col];
          const int bi = row >> 10, t = row & 1023, h = col >> 6, dd = col & 63;
          dst[((size_t)(bi * 16 + h) * 1024 + t) * 64 + dd] = f2b(v);
        }
  }
}

// Output projection: x = concat@Wo^T + bo + query   (f32)
__global__ __launch_bounds__(256) void gemm_out(
    const ushort_t* __restrict__ A, const ushort_t* __restrict__ Bt,
    const float* __restrict__ bias, const float* __restrict__ resid,
    float* __restrict__ dstF) {
  __shared__ ushort_t As[128 * 32], Bs[128 * 32];
  const int m0 = blockIdx.y * 128, n0 = blockIdx.x * 128;
  f32x4 zero = {0.f, 0.f, 0.f, 0.f};
  f32x4 acc[4][4];
  #pragma unroll
  for (int m = 0; m < 4; ++m)
    #pragma unroll
    for (int n = 0; n < 4; ++n) acc[m][n] = zero;
  gemm_core(A, Bt, m0, n0, As, Bs, acc);
  const int lane = threadIdx.x & 63, wid = threadIdx.x >> 6;
  const int wr = (wid >> 1) * 64, wc = (wid & 1) * 64;
  #pragma unroll
  for (int m = 0; m < 4; ++m)
    #pragma unroll
    for (int n = 0; n < 4; ++n)
      #pragma unroll
      for (int r4 = 0; r4 < 4; ++r4) {
        const int row = m0 + wr + m * 16 + (lane >> 4) * 4 + r4;
        const int col = n0 + wc + n * 16 + (lane & 15);
        const size_t o = (size_t)row * 1024 + col;
        dstF[o] = acc[m][n][r4] + bias[col] + resid[o];
      }
}

// ---------------------------------------------------------------------------
// Width-adaptive aligned LDS row access for Phase B.  Row points at col c0 of
// a plain [16][1032]-ushort S buffer; c0 = CH*lane keeps W-alignment per CH.
// ---------------------------------------------------------------------------
template<int CH>
__device__ __forceinline__ void load_row(const ushort_t* __restrict__ Row, float (&s)[CH]) {
  constexpr int W = (CH % 8 == 0) ? 8 : (CH % 4 == 0) ? 4 : (CH % 2 == 0) ? 2 : 1;
  #pragma unroll
  for (int b = 0; b < CH / W; ++b) {
    if constexpr (W == 8) {
      const u16x8 t = *reinterpret_cast<const u16x8*>(&Row[b * 8]);
      #pragma unroll
      for (int e = 0; e < 8; ++e) s[b * 8 + e] = b2f(t[e]);
    } else if constexpr (W == 4) {
      const u16x4 t = *reinterpret_cast<const u16x4*>(&Row[b * 4]);
      #pragma unroll
      for (int e = 0; e < 4; ++e) s[b * 4 + e] = b2f(t[e]);
    } else if constexpr (W == 2) {
      const u16x2 t = *reinterpret_cast<const u16x2*>(&Row[b * 2]);
      s[b * 2] = b2f(t[0]); s[b * 2 + 1] = b2f(t[1]);
    } else {
      s[b] = b2f(Row[b]);
    }
  }
}

template<int CH>
__device__ __forceinline__ void store_row(ushort_t* __restrict__ Row,
                                          const float (&p)[CH], const float sc) {
  constexpr int W = (CH % 8 == 0) ? 8 : (CH % 4 == 0) ? 4 : (CH % 2 == 0) ? 2 : 1;
  #pragma unroll
  for (int b = 0; b < CH / W; ++b) {
    if constexpr (W == 8) {
      u16x8 o;
      #pragma unroll
      for (int e = 0; e < 8; ++e) o[e] = f2b(p[b * 8 + e] * sc);
      *reinterpret_cast<u16x8*>(&Row[b * 8]) = o;
    } else if constexpr (W == 4) {
      u16x4 o;
      #pragma unroll
      for (int e = 0; e < 4; ++e) o[e] = f2b(p[b * 4 + e] * sc);
      *reinterpret_cast<u16x4*>(&Row[b * 4]) = o;
    } else if constexpr (W == 2) {
      u16x2 o;
      o[0] = f2b(p[b * 2] * sc); o[1] = f2b(p[b * 2 + 1] * sc);
      *reinterpret_cast<u16x2*>(&Row[b * 2]) = o;
    } else {
      Row[b] = f2b(p[b] * sc);
    }
  }
}

// ---------------------------------------------------------------------------
// Phase B worker, CH columns per lane (lane L owns cols [CH*L, CH*(L+1))).
// 4 waves, 4 rows per wave.  s[CH] + ev[CH] live; 3 exp2 per element.
// ---------------------------------------------------------------------------
template<int CH>
__device__ __forceinline__ void phase_b(ushort_t* __restrict__ Sb, const int i0,
                                        const int w, const int lane, const float gamx) {
  const int c0 = CH * lane;
  for (int rr = 0; rr < 4; ++rr) {
    const int r = w * 4 + rr;
    const int i = i0 + r;
    ushort_t* __restrict__ Row = &Sb[r * 1032 + c0];
    if (i == 0) {                       // fully masked row -> P = 0
      #pragma unroll
      for (int e = 0; e < CH; ++e) Row[e] = 0;
      continue;
    }
    const int nact = min(max(i - c0, 0), CH);
    float s[CH], ev[CH];
    load_row<CH>(Row, s);
    // mask + first exp (no max-sub; scores are O(1)) + in-lane total
    float run = 0.f;
    #pragma unroll
    for (int e = 0; e < CH; ++e) {
      s[e] = (e < nact) ? s[e] * LOG2E : -__builtin_inff();
      ev[e] = EXP2F(s[e]);              // exact 0 for masked
      run += ev[e];
    }
    // wave-level inclusive suffix of lane totals -> Z1, exclusive tail
    float v = run;
    #pragma unroll
    for (int d = 1; d < 64; d <<= 1) {
      const float t = __shfl_down(v, d);
      v += (lane + d < 64) ? t : 0.f;
    }
    const float Z1 = __shfl(v, 0);
    float run2 = v - run;               // tail beyond this lane's span
    // gamma effect + second exp + fused z2/mm accumulation (single pass)
    const float g2 = -gamx * rsqrtf(Z1);
    const float posb = (float)(i - c0);
    float z2 = 0.f, mm = 0.f;
    #pragma unroll
    for (int e = CH - 1; e >= 0; --e) {
      const float t = fmaxf(run2 * (posb - (float)e), 0.f);
      run2 += ev[e];
      const float eff = fmaxf(EXP2F(g2 * sqrtf(t)), 1e-5f);
      const float p = EXP2F(s[e] * eff);   // -inf stays -inf -> p = 0
      ev[e] = p;
      z2 += p;
      mm = fmaxf(mm, p);
    }
    #pragma unroll
    for (int d = 32; d > 0; d >>= 1) {
      z2 += __shfl_xor(z2, d);
      mm = fmaxf(mm, __shfl_xor(mm, d));
    }
    const float sc = fminf(1.f / mm, 5.f / z2);   // maxout-combined normalizer
    store_row<CH>(Row, ev, sc);
  }
}

// ---------------------------------------------------------------------------
// Attention.  grid = (64, 64) remapped: one bh-group per XCD, heaviest i0
// first.  256 threads (4 waves).  S plain [16][1032] bf16.
// ---------------------------------------------------------------------------
__global__ __launch_bounds__(256, 4) void attn_kernel(
    const ushort_t* __restrict__ Qh, const ushort_t* __restrict__ Kh,
    const ushort_t* __restrict__ Vt, const float* __restrict__ gammas,
    ushort_t* __restrict__ concat) {
  __shared__ __align__(16) ushort_t Sb[16 * 1032];
  __shared__ __align__(16) ushort_t Qs[16 * 72];     // padded stride 72
  const int tid = threadIdx.x, lane = tid & 63, w = tid >> 6;
  // XCD swizzle: flat%8 picks XCD (round-robin dispatch); one bh-octet per
  // XCD; i0 reversed so heaviest blocks dispatch first (tail packing).
  const int flat = blockIdx.x + (blockIdx.y << 6);
  const int bh = ((flat & 7) << 3) | (flat >> 9);
  const int i0 = (63 - ((flat >> 3) & 63)) << 4;
  const int bi = bh >> 4, h = bh & 15;
  const size_t base = (size_t)bh * (1024 * 64);

  { // stage Q tile (16 rows x 64)
    const int r = tid >> 4, d = (tid & 15) * 4;
    *reinterpret_cast<u16x4*>(&Qs[r * 72 + d]) =
        *reinterpret_cast<const u16x4*>(&Qh[base + (size_t)(i0 + r) * 64 + d]);
  }
  __syncthreads();

  // ---- Phase A: scores -> bf16 S ----
  const int upper = i0 + 16;
  for (int nt = 0; nt < 16; ++nt) {
    const int colbase = (nt * 4 + w) * 16;
    if (colbase >= upper) break;
    f32x4 acc = {0.f, 0.f, 0.f, 0.f};
    #pragma unroll
    for (int kt = 0; kt < 2; ++kt) {
      const short8 a = *reinterpret_cast<const short8*>(
          &Qs[(lane & 15) * 72 + kt * 32 + (lane >> 4) * 8]);
      const short8 bb = *reinterpret_cast<const short8*>(
          &Kh[base + (size_t)(colbase + (lane & 15)) * 64 + kt * 32 + (lane >> 4) * 8]);
      acc = __builtin_amdgcn_mfma_f32_16x16x32_bf16(a, bb, acc, 0, 0, 0);
    }
    const int j = colbase + (lane & 15);
    #pragma unroll
    for (int r4 = 0; r4 < 4; ++r4) {
      const int rf = (lane >> 4) * 4 + r4;
      Sb[rf * 1032 + j] = f2b(acc[r4] * 0.125f);
    }
  }
  __syncthreads();

  // ---- Phase B: exact-even causal tiering, 4 rows/wave ----
  const float gamx = fabsf(gammas[h]) * LOG2E;
  const int chp = (upper + 63) >> 6;        // col-blocks needed (block-uniform)
  switch (chp) {
    case 1:           phase_b<1 >(Sb, i0, w, lane, gamx); break;
    case 2:           phase_b<2 >(Sb, i0, w, lane, gamx); break;
    case 3: case 4:   phase_b<4 >(Sb, i0, w, lane, gamx); break;
    case 5: case 6:   phase_b<6 >(Sb, i0, w, lane, gamx); break;
    case 7: case 8:   phase_b<8 >(Sb, i0, w, lane, gamx); break;
    case 9: case 10:  phase_b<10>(Sb, i0, w, lane, gamx); break;
    case 11: case 12: phase_b<12>(Sb, i0, w, lane, gamx); break;
    case 13: case 14: phase_b<14>(Sb, i0, w, lane, gamx); break;
    default:          phase_b<16>(Sb, i0, w, lane, gamx); break;
  }
  __syncthreads();

  // ---- Phase C: PV via MFMA.  wave w -> d-tile d0 = w*16 ----
  {
    const int d0 = w * 16;
    const int arow = lane & 15;
    const ushort_t* Prow = &Sb[arow * 1032];
    const ushort_t* Vrow = Vt + base + (size_t)(d0 + arow) * 1024;
    const int kmax = (upper + 31) & ~31;
    f32x4 acc = {0.f, 0.f, 0.f, 0.f};
    for (int k0 = 0; k0 < kmax; k0 += 32) {
      const short8 a = *reinterpret_cast<const short8*>(&Prow[k0 + (lane >> 4) * 8]);
      const short8 bb = *reinterpret_cast<const short8*>(&Vrow[k0 + (lane >> 4) * 8]);
      acc = __builtin_amdgcn_mfma_f32_16x16x32_bf16(a, bb, acc, 0, 0, 0);
    }
    #pragma unroll
    for (int r4 = 0; r4 < 4; ++r4) {
      const int row = (lane >> 4) * 4 + r4;
      const int i = i0 + row;
      concat[((size_t)(bi * 1024 + i)) * 1024 + h * 64 + d0 + arow] = f2b(acc[r4]);
    }
  }
}

// ---------------------------------------------------------------------------
__global__ __launch_bounds__(256) void ln_kernel(const float* __restrict__ x,
                                                 const float* __restrict__ g,
                                                 const float* __restrict__ bb,
                                                 float* __restrict__ out) {
  const int row = blockIdx.x, tid = threadIdx.x, lane = tid & 63, w = tid >> 6;
  const float4 v = reinterpret_cast<const float4*>(x + (size_t)row * 1024)[tid];
  float s = v.x + v.y + v.z + v.w;
  float q = v.x * v.x + v.y * v.y + v.z * v.z + v.w * v.w;
  s = wave_sum(s); q = wave_sum(q);
  __shared__ float ps[4], pq[4];
  if (lane == 0) { ps[w] = s; pq[w] = q; }
  __syncthreads();
  const float ts = ps[0] + ps[1] + ps[2] + ps[3];
  const float tq = pq[0] + pq[1] + pq[2] + pq[3];
  const float mu = ts * (1.f / 1024.f);
  const float inv = rsqrtf(tq * (1.f / 1024.f) - mu * mu + 1e-5f);
  const float4 gv = reinterpret_cast<const float4*>(g)[tid];
  const float4 bv = reinterpret_cast<const float4*>(bb)[tid];
  float4 o;
  o.x = (v.x - mu) * inv * gv.x + bv.x;
  o.y = (v.y - mu) * inv * gv.y + bv.y;
  o.z = (v.z - mu) * inv * gv.z + bv.z;
  o.w = (v.w - mu) * inv * gv.w + bv.w;
  reinterpret_cast<float4*>(out + (size_t)row * 1024)[tid] = o;
}

// ---------------------------------------------------------------------------
extern "C" void kernel_launch(void* const* d_in, const int* in_sizes, int n_in,
                              void* d_out, int out_size, void* d_ws, size_t ws_size,
                              hipStream_t stream) {
  (void)in_sizes; (void)n_in; (void)out_size; (void)ws_size;
  const float* query  = (const float*)d_in[0];
  const float* key    = (const float*)d_in[1];
  const float* values = (const float*)d_in[2];
  const float* Wq     = (const float*)d_in[3];
  const float* bq     = (const float*)d_in[4];
  const float* Wv     = (const float*)d_in[5];
  const float* bv     = (const float*)d_in[6];
  const float* Wo     = (const float*)d_in[7];
  const float* bo     = (const float*)d_in[8];
  const float* gammas = (const float*)d_in[9];
  const float* ln_g   = (const float*)d_in[10];
  const float* ln_b   = (const float*)d_in[11];
  float* out = (float*)d_out;

  const size_t NT = 4096ull * 1024;
  const size_t NW = 1024ull * 1024;
  char* p = (char*)d_ws;
  ushort_t* qb  = (ushort_t*)p; p += NT * 2;
  ushort_t* kb  = (ushort_t*)p; p += NT * 2;
  ushort_t* vb  = (ushort_t*)p; p += NT * 2;
  ushort_t* Wqb = (ushort_t*)p; p += NW * 2;
  ushort_t* Wvb = (ushort_t*)p; p += NW * 2;
  ushort_t* Wob = (ushort_t*)p; p += NW * 2;
  ushort_t* Qh  = (ushort_t*)p; p += NT * 2;
  ushort_t* Kh  = (ushort_t*)p; p += NT * 2;
  ushort_t* Vt  = (ushort_t*)p; p += NT * 2;
  ushort_t* concat = vb;                // free after gemm_proj
  float*    xbuf   = (float*)qb;        // spans qb+kb, free after gemm_proj

  conv6_f32_bf16<<<dim3(4096, 6), 256, 0, stream>>>(
      query, key, values, Wq, Wv, Wo, qb, kb, vb, Wqb, Wvb, Wob,
      (int)(NT / 4), (int)(NW / 4));

  gemm_proj<<<dim3(8, 32, 3), 256, 0, stream>>>(qb, kb, vb, Wqb, Wvb, bq, bv, Qh, Kh, Vt);
  attn_kernel<<<dim3(64, 64), 256, 0, stream>>>(Qh, Kh, Vt, gammas, concat);
  gemm_out<<<dim3(8, 32), 256, 0, stream>>>(concat, Wob, bo, query, xbuf);
  ln_kernel<<<4096, 256, 0, stream>>>(xbuf, ln_g, ln_b, out);
}